// Round 10
// baseline (673.639 us; speedup 1.0000x reference)
//
#include <hip/hip_runtime.h>
#include <hip/hip_bf16.h>

#define HOPS 3
#define NA 50000
#define NP 100000
#define NIN 256
#define NHID 128
#define NOUT 64
#define CAP_A 64
#define CAP_P 40

typedef __attribute__((ext_vector_type(8))) short bf16x8;
typedef __attribute__((ext_vector_type(4))) float f32x4;
typedef unsigned short ushort_t;

__device__ inline short f2bf(float f) {
    __hip_bfloat16 h = __float2bfloat16(f);
    return *reinterpret_cast<short*>(&h);
}
__device__ inline float bf2f(unsigned short u) {
    unsigned v = ((unsigned)u) << 16;
    return __uint_as_float(v);
}
// paired fma on a float2 — pattern the compiler can map to v_pk_fma_f32
__device__ inline float2 pkfma(float w, float2 a, float2 c) {
    c.x = fmaf(w, a.x, c.x);
    c.y = fmaf(w, a.y, c.y);
    return c;
}

// ---------- weight transposes+converts (W1_A, W1_P only) ----------
__global__ void prep_all(const float* __restrict__ W1_A, const float* __restrict__ W1_P,
                         short* __restrict__ WtA, short* __restrict__ WtP)
{
    int idx = blockIdx.x * 256 + threadIdx.x;
    const int S1 = NHID * NIN;
    if (idx < S1) {
        int n = idx / NIN, k = idx - n * NIN;
        WtA[idx] = f2bf(W1_A[(size_t)k * NHID + n]);
    } else if (idx < 2 * S1) {
        int j = idx - S1;
        int n = j / NIN, k = j - n * NIN;
        WtP[j] = f2bf(W1_P[(size_t)k * NHID + n]);
    }
}

// ---------- projection (round-2 measured-best structure) ----------
// writes f32 (wf32=1) or bf16 (wf32=0)
__global__ __launch_bounds__(256) void proj_mfma(const float* __restrict__ A,
                                                 const short* __restrict__ Wt,
                                                 const float* __restrict__ b,
                                                 float* __restrict__ Cf,
                                                 ushort_t* __restrict__ Cb,
                                                 int M, int wf32)
{
    __shared__ short Alds[64][40];
    __shared__ short Wlds[128][40];
    int tid = threadIdx.x;
    int br = blockIdx.x * 64;
    int wv = tid >> 6;
    int l = tid & 63;
    int fl = l & 15;
    int kg = l >> 4;

    int sr = tid >> 2;
    int skp = (tid & 3) * 8;
    int sgr = br + sr; if (sgr >= M) sgr = M - 1;
    int sn = tid >> 1;
    int skq = (tid & 1) * 16;

    f32x4 acc[8];
    #pragma unroll
    for (int c = 0; c < 8; ++c) acc[c] = (f32x4){0.f, 0.f, 0.f, 0.f};

    for (int k0 = 0; k0 < NIN; k0 += 32) {
        const float4* ap = (const float4*)(A + (size_t)sgr * NIN + k0 + skp);
        float4 v0 = ap[0], v1 = ap[1];
        union { short s[8]; int4 v; } pk;
        pk.s[0] = f2bf(v0.x); pk.s[1] = f2bf(v0.y);
        pk.s[2] = f2bf(v0.z); pk.s[3] = f2bf(v0.w);
        pk.s[4] = f2bf(v1.x); pk.s[5] = f2bf(v1.y);
        pk.s[6] = f2bf(v1.z); pk.s[7] = f2bf(v1.w);
        *(int4*)&Alds[sr][skp] = pk.v;
        const int4* wp = (const int4*)(Wt + (size_t)sn * NIN + k0 + skq);
        int4 w0 = wp[0], w1 = wp[1];
        *(int4*)&Wlds[sn][skq] = w0;
        *(int4*)&Wlds[sn][skq + 8] = w1;
        __syncthreads();

        bf16x8 afr = *(bf16x8*)&Alds[wv * 16 + fl][kg * 8];
        #pragma unroll
        for (int c = 0; c < 8; ++c) {
            bf16x8 bfr = *(bf16x8*)&Wlds[c * 16 + fl][kg * 8];
            acc[c] = __builtin_amdgcn_mfma_f32_16x16x32_bf16(afr, bfr, acc[c], 0, 0, 0);
        }
        __syncthreads();
    }

    int rj = kg * 4;
    #pragma unroll
    for (int c = 0; c < 8; ++c) {
        int col = c * 16 + fl;
        float bb = b[col];
        #pragma unroll
        for (int j = 0; j < 4; ++j) {
            int grow = br + wv * 16 + rj + j;
            if (grow < M) {
                float v = fmaxf(acc[c][j] + bb, 0.f);
                if (wf32) Cf[(size_t)grow * NHID + col] = v;
                else      Cb[(size_t)grow * NHID + col] = (ushort_t)f2bf(v);
            }
        }
    }
}

// ---------- output: C[M,64] = A[M,128] @ W + b (f32 VALU, round-1 version) ----------
__global__ __launch_bounds__(256) void out_kernel(const float* __restrict__ A,
                                                  const float* __restrict__ W,
                                                  const float* __restrict__ b,
                                                  float* __restrict__ C, int M)
{
    __shared__ float As[32][68];
    __shared__ float Bs[32][68];
    int tid = threadIdx.x;
    int br = blockIdx.x * 64;
    int tx = tid & 15, ty = tid >> 4;
    int col = tx * 4, row0 = ty * 4;
    float acc[4][4] = {};
    for (int k0 = 0; k0 < NHID; k0 += 32) {
        #pragma unroll
        for (int i = 0; i < 2; ++i) {
            int f = tid + i * 256;
            int r = f >> 3;
            int k4 = (f & 7) * 4;
            int gr = br + r; if (gr >= M) gr = M - 1;
            const float4 v = *(const float4*)(A + (size_t)gr * NHID + k0 + k4);
            As[k4 + 0][r] = v.x; As[k4 + 1][r] = v.y;
            As[k4 + 2][r] = v.z; As[k4 + 3][r] = v.w;
        }
        #pragma unroll
        for (int i = 0; i < 2; ++i) {
            int f = tid + i * 256;
            int k = f >> 4;
            int n4 = (f & 15) * 4;
            const float4 v = *(const float4*)(W + (size_t)(k0 + k) * NOUT + n4);
            *(float4*)&Bs[k][n4] = v;
        }
        __syncthreads();
        #pragma unroll
        for (int kk = 0; kk < 32; ++kk) {
            float4 a = *(const float4*)&As[kk][row0];
            float4 bv = *(const float4*)&Bs[kk][col];
            float ar[4] = {a.x, a.y, a.z, a.w};
            float bc[4] = {bv.x, bv.y, bv.z, bv.w};
            #pragma unroll
            for (int r = 0; r < 4; ++r)
                #pragma unroll
                for (int c = 0; c < 4; ++c)
                    acc[r][c] += ar[r] * bc[c];
        }
        __syncthreads();
    }
    float4 bias = *(const float4*)(b + col);
    float bb[4] = {bias.x, bias.y, bias.z, bias.w};
    #pragma unroll
    for (int r = 0; r < 4; ++r) {
        int gr = br + row0 + r;
        if (gr < M) {
            float4 o = {acc[r][0] + bb[0], acc[r][1] + bb[1],
                        acc[r][2] + bb[2], acc[r][3] + bb[3]};
            *(float4*)(C + (size_t)gr * NOUT + col) = o;
        }
    }
}

// ---------- merged padded-CSR fill ----------
__global__ void fill_kernel(const int* __restrict__ sA, const int* __restrict__ tA,
                            const int* __restrict__ sP, const int* __restrict__ tP,
                            int* __restrict__ cntA, int* __restrict__ slotsA,
                            int* __restrict__ cntP, int* __restrict__ slotsP, int nE)
{
    int e = blockIdx.x * 256 + threadIdx.x;
    if (e < nE) {
        int si = sA[e];
        int c = atomicAdd(&cntA[si], 1);
        if (c < CAP_A) slotsA[(size_t)si * CAP_A + c] = tA[e];
    } else if (e < 2 * nE) {
        int k = e - nE;
        int si = sP[k];
        int c = atomicAdd(&cntP[si], 1);
        if (c < CAP_P) slotsP[(size_t)si * CAP_P + c] = tP[k];
    }
}

// ---------- merged x-side scalars for ALL hops ----------
__global__ void xdots_kernel(const float* __restrict__ xA, const void* __restrict__ xPv,
                             const float* __restrict__ attn1, const float* __restrict__ attn2,
                             float* __restrict__ x1A, float* __restrict__ w2A, float* __restrict__ h1Ai,
                             float* __restrict__ x1P, float* __restrict__ w2P, float* __restrict__ h1Pi,
                             int FULL)
{
    int wid = (blockIdx.x * blockDim.x + threadIdx.x) >> 6;
    int lane = threadIdx.x & 63;
    if (wid >= NA + NP) return;
    bool isA = wid < NA;
    int n = isA ? wid : wid - NA;
    int etype = isA ? 0 : 1;
    float xa, xb;
    if (isA) {
        float2 xv = *(const float2*)(xA + (size_t)n * NHID + lane * 2);
        xa = xv.x; xb = xv.y;
    } else if (FULL) {
        float2 xv = *(const float2*)((const float*)xPv + (size_t)n * NHID + lane * 2);
        xa = xv.x; xb = xv.y;
    } else {
        unsigned q = *(const unsigned*)((const ushort_t*)xPv + (size_t)n * NHID + lane * 2);
        xa = __uint_as_float(q << 16);
        xb = __uint_as_float(q & 0xffff0000u);
    }
    float s[7];
    #pragma unroll
    for (int i = 0; i < 3; ++i) {
        float2 a1v = *(const float2*)(attn1 + (size_t)(i * 2 + etype) * NHID + lane * 2);
        float2 a2v = *(const float2*)(attn2 + (size_t)(i * 2 + etype) * NHID + lane * 2);
        s[i]     = xa * a1v.x + xb * a1v.y;
        s[3 + i] = xa * a2v.x + xb * a2v.y;
    }
    float2 a2o = *(const float2*)(attn2 + (size_t)(1 - etype) * NHID + lane * 2);
    s[6] = xa * a2o.x + xb * a2o.y;
    #pragma unroll
    for (int m = 32; m; m >>= 1)
        #pragma unroll
        for (int i = 0; i < 7; ++i) s[i] += __shfl_xor(s[i], m, 64);
    if (lane == 0) {
        int N = isA ? NA : NP;
        float* x1 = isA ? x1A : x1P;
        float* w2 = isA ? w2A : w2P;
        #pragma unroll
        for (int i = 0; i < 3; ++i) {
            x1[(size_t)i * N + n] = s[i];
            float v = s[i] + s[3 + i];
            v = v > 0.f ? v : 0.2f * v;
            w2[(size_t)i * N + n] = __expf(v);
        }
        (isA ? h1Ai : h1Pi)[n] = s[6];
    }
}

// ---------- fused A+P aggregation: 16 feature-lanes x 4 edge-groups ----------
// hA gather source is always f32; hP gather source is f32 (FULL) or bf16.
__global__ __launch_bounds__(256) void agg_fused(
    const float* __restrict__ xA, const void* __restrict__ xPv,
    const float* __restrict__ hA_src, const void* __restrict__ hP_src,
    const float* __restrict__ x1Ah, const float* __restrict__ x1Ph,
    const float* __restrict__ w2Ah, const float* __restrict__ w2Ph,
    const float* __restrict__ h1Agc, const float* __restrict__ h1Pgc,
    const int* __restrict__ cntA, const int* __restrict__ slotsA,
    const int* __restrict__ cntP, const int* __restrict__ slotsP,
    const float* __restrict__ a2nA, const float* __restrict__ a2nP,
    float* __restrict__ hAout, void* __restrict__ hPoutv,
    float* __restrict__ h1Aout, float* __restrict__ h1Pout,
    int nodes, int FULL)
{
    int wid = (blockIdx.x * blockDim.x + threadIdx.x) >> 6;
    int lane = threadIdx.x & 63;
    if (wid >= nodes) return;
    int g = lane >> 4, fl = lane & 15;
    bool isA = wid < NA;
    int n = isA ? wid : wid - NA;
    int deg; const int* sl; const float* h1g; float x1v;
    if (isA) {
        deg = cntA[n]; if (deg > CAP_A) deg = CAP_A;
        sl = slotsA + (size_t)n * CAP_A; h1g = h1Pgc; x1v = x1Ah[n];
    } else {
        deg = cntP[n]; if (deg > CAP_P) deg = CAP_P;
        sl = slotsP + (size_t)n * CAP_P; h1g = h1Agc; x1v = x1Ph[n];
    }

    // cooperative preload: lane l holds edge l's (t, w)
    int t_l = 0;
    float w_l = 0.f;
    if (deg > 0) {
        int idx = lane < deg ? lane : deg - 1;
        t_l = sl[idx];
        if (lane < deg) {
            float v = x1v + h1g[t_l];
            v = v > 0.f ? v : 0.2f * v;
            w_l = __expf(v);
        }
    }
    float div = w_l;
    #pragma unroll
    for (int m = 1; m <= 32; m <<= 1) div += __shfl_xor(div, m, 64);

    float2 a0 = {0.f, 0.f}, a1 = {0.f, 0.f}, a2v_ = {0.f, 0.f}, a3 = {0.f, 0.f};
    int R = (deg + 3) >> 2;
    bool srcF32 = (!isA) || FULL;

    if (srcF32) {
        const float* hf = isA ? (const float*)hP_src : hA_src;
        float4 ra = {0, 0, 0, 0}, rb = {0, 0, 0, 0};
        if (R > 0) {
            int t0 = __shfl(t_l, g, 64);
            const float4* p = (const float4*)(hf + (size_t)t0 * NHID + fl * 8);
            ra = p[0]; rb = p[1];
        }
        for (int r = 0; r < R; ++r) {
            float w = __shfl(w_l, r * 4 + g, 64);
            float4 ca = ra, cb = rb;
            if (r + 1 < R) {
                int tn = __shfl(t_l, (r + 1) * 4 + g, 64);
                const float4* p = (const float4*)(hf + (size_t)tn * NHID + fl * 8);
                ra = p[0]; rb = p[1];
            }
            a0 = pkfma(w, make_float2(ca.x, ca.y), a0);
            a1 = pkfma(w, make_float2(ca.z, ca.w), a1);
            a2v_ = pkfma(w, make_float2(cb.x, cb.y), a2v_);
            a3 = pkfma(w, make_float2(cb.z, cb.w), a3);
        }
    } else {
        const ushort_t* hb = (const ushort_t*)hP_src;
        int4 ra = {0, 0, 0, 0};
        if (R > 0) {
            int t0 = __shfl(t_l, g, 64);
            ra = *(const int4*)(hb + (size_t)t0 * NHID + fl * 8);
        }
        for (int r = 0; r < R; ++r) {
            float w = __shfl(w_l, r * 4 + g, 64);
            int4 cur = ra;
            if (r + 1 < R) {
                int tn = __shfl(t_l, (r + 1) * 4 + g, 64);
                ra = *(const int4*)(hb + (size_t)tn * NHID + fl * 8);
            }
            unsigned q0 = (unsigned)cur.x, q1 = (unsigned)cur.y;
            unsigned q2 = (unsigned)cur.z, q3 = (unsigned)cur.w;
            a0 = pkfma(w, make_float2(__uint_as_float(q0 << 16), __uint_as_float(q0 & 0xffff0000u)), a0);
            a1 = pkfma(w, make_float2(__uint_as_float(q1 << 16), __uint_as_float(q1 & 0xffff0000u)), a1);
            a2v_ = pkfma(w, make_float2(__uint_as_float(q2 << 16), __uint_as_float(q2 & 0xffff0000u)), a2v_);
            a3 = pkfma(w, make_float2(__uint_as_float(q3 << 16), __uint_as_float(q3 & 0xffff0000u)), a3);
        }
    }

    // combine the 4 groups; afterwards EVERY lane holds full sums for its fl
    #pragma unroll
    for (int m = 16; m <= 32; m <<= 1) {
        a0 += make_float2(__shfl_xor(a0.x, m, 64), __shfl_xor(a0.y, m, 64));
        a1 += make_float2(__shfl_xor(a1.x, m, 64), __shfl_xor(a1.y, m, 64));
        a2v_ += make_float2(__shfl_xor(a2v_.x, m, 64), __shfl_xor(a2v_.y, m, 64));
        a3 += make_float2(__shfl_xor(a3.x, m, 64), __shfl_xor(a3.y, m, 64));
    }

    // all-lane epilogue: lane (g,fl) finishes features fl*8 + 2g, 2g+1
    float2 pr = (g == 0) ? a0 : (g == 1) ? a1 : (g == 2) ? a2v_ : a3;

    float w2v = isA ? w2Ah[n] : w2Ph[n];
    float2 xv;
    if (isA) {
        xv = *(const float2*)(xA + (size_t)n * NHID + fl * 8 + 2 * g);
    } else if (FULL) {
        xv = *(const float2*)((const float*)xPv + (size_t)n * NHID + fl * 8 + 2 * g);
    } else {
        unsigned xq = *(const unsigned*)((const ushort_t*)xPv + (size_t)n * NHID + fl * 8 + 2 * g);
        xv = make_float2(__uint_as_float(xq << 16), __uint_as_float(xq & 0xffff0000u));
    }
    pr = pkfma(w2v, xv, pr);
    float dv = div + w2v;
    float inv = 1.f / dv;
    float vlo = pr.x * inv, vhi = pr.y * inv;
    float olo = vlo > 0.f ? vlo : (__expf(vlo) - 1.f);
    float ohi = vhi > 0.f ? vhi : (__expf(vhi) - 1.f);

    // next-hop h1 dot (full-wave)
    const float* a2 = isA ? a2nA : a2nP;
    float2 av = *(const float2*)(a2 + fl * 8 + 2 * g);
    float s = olo * av.x + ohi * av.y;
    #pragma unroll
    for (int m = 1; m <= 32; m <<= 1) s += __shfl_xor(s, m, 64);

    if (isA) {
        *(float2*)(hAout + (size_t)n * NHID + fl * 8 + 2 * g) = make_float2(olo, ohi);
    } else if (FULL) {
        *(float2*)((float*)hPoutv + (size_t)n * NHID + fl * 8 + 2 * g) = make_float2(olo, ohi);
    } else {
        unsigned plo = ((unsigned)(ushort_t)f2bf(olo));
        unsigned phi = ((unsigned)(ushort_t)f2bf(ohi)) << 16;
        ((unsigned*)((ushort_t*)hPoutv + (size_t)n * NHID))[fl * 4 + g] = plo | phi;
    }
    if (lane == 0) (isA ? h1Aout : h1Pout)[n] = s;
}

extern "C" void kernel_launch(void* const* d_in, const int* in_sizes, int n_in,
                              void* d_out, int out_size, void* d_ws, size_t ws_size,
                              hipStream_t stream)
{
    const float* x_A  = (const float*)d_in[0];
    const float* x_P  = (const float*)d_in[1];
    const int*   sAP  = (const int*)d_in[2];
    const int*   tAP  = (const int*)d_in[3];
    const int*   sPA  = (const int*)d_in[4];
    const int*   tPA  = (const int*)d_in[5];
    const float* W1_A = (const float*)d_in[6];
    const float* b1_A = (const float*)d_in[7];
    const float* W1_P = (const float*)d_in[8];
    const float* b1_P = (const float*)d_in[9];
    const float* attn1 = (const float*)d_in[10];
    const float* attn2 = (const float*)d_in[11];
    const float* W2   = (const float*)d_in[12];
    const float* b2   = (const float*)d_in[13];
    float* out = (float*)d_out;
    int nE = in_sizes[2];

    char* ws = (char*)d_ws;
    size_t off = 0;
    auto alloc = [&](size_t bytes) -> void* {
        void* p = ws + off;
        off += (bytes + 255) & ~(size_t)255;
        return p;
    };

    const int FULL = (ws_size >= (size_t)275 * 1024 * 1024) ? 1 : 0;

    float* xA = (float*)alloc((size_t)NA * NHID * 4);          // f32 always
    void* xP;                                                   // f32 (FULL) or bf16
    if (FULL) xP = alloc((size_t)NP * NHID * 4);
    else      xP = alloc((size_t)NP * NHID * 2);
    float* hA[2] = {(float*)alloc((size_t)NA * NHID * 4),
                    (float*)alloc((size_t)NA * NHID * 4)};
    void* hP[2];
    if (FULL) { hP[0] = alloc((size_t)NP * NHID * 4); hP[1] = alloc((size_t)NP * NHID * 4); }
    else      { hP[0] = alloc((size_t)NP * NHID * 2); hP[1] = alloc((size_t)NP * NHID * 2); }
    float* x1A = (float*)alloc((size_t)3 * NA * 4);
    float* w2A = (float*)alloc((size_t)3 * NA * 4);
    float* x1P = (float*)alloc((size_t)3 * NP * 4);
    float* w2P = (float*)alloc((size_t)3 * NP * 4);
    float* h1Ai = (float*)alloc(NA * 4);
    float* h1Pi = (float*)alloc(NP * 4);
    float* h1Ab[2] = {(float*)alloc(NA * 4), (float*)alloc(NA * 4)};
    float* h1Pb[2] = {(float*)alloc(NP * 4), (float*)alloc(NP * 4)};
    int* cntA  = (int*)alloc(NA * 4);
    int* cntP  = (int*)alloc(NP * 4);
    int* slotsA = (int*)alloc((size_t)NA * CAP_A * 4);
    int* slotsP = (int*)alloc((size_t)NP * CAP_P * 4);
    short* WtA = (short*)alloc((size_t)NHID * NIN * 2);
    short* WtP = (short*)alloc((size_t)NHID * NIN * 2);

    // padded CSR (edge structure reused by all hops)
    hipMemsetAsync(cntA, 0, NA * 4, stream);
    hipMemsetAsync(cntP, 0, NP * 4, stream);
    fill_kernel<<<(2 * nE + 255) / 256, 256, 0, stream>>>(sAP, tAP, sPA, tPA,
                                                          cntA, slotsA, cntP, slotsP, nE);

    // weights -> bf16 transposed
    prep_all<<<(2 * NHID * NIN + 255) / 256, 256, 0, stream>>>(W1_A, W1_P, WtA, WtP);

    // projections -> h0 (A: f32; P: f32 if FULL else bf16)
    proj_mfma<<<(NA + 63) / 64, 256, 0, stream>>>(x_A, WtA, b1_A,
                                                  xA, (ushort_t*)nullptr, NA, 1);
    proj_mfma<<<(NP + 63) / 64, 256, 0, stream>>>(x_P, WtP, b1_P,
                                                  (float*)xP, (ushort_t*)xP, NP, FULL);

    // x-side scalars for all hops (merged)
    xdots_kernel<<<(NA + NP + 3) / 4, 256, 0, stream>>>(
        xA, xP, attn1, attn2, x1A, w2A, h1Ai, x1P, w2P, h1Pi, FULL);

    const float* hAg = xA;
    const void*  hPg = xP;
    const float* h1Ac = h1Ai;
    const float* h1Pc = h1Pi;

    for (int i = 0; i < HOPS; ++i) {
        int last = (i == HOPS - 1);
        int nodes = last ? NA : (NA + NP);
        const float* a2nA_ = last ? attn2 : attn2 + (size_t)((i + 1) * 2 + 1) * NHID;
        const float* a2nP_ = last ? attn2 : attn2 + (size_t)((i + 1) * 2 + 0) * NHID;
        agg_fused<<<(nodes + 3) / 4, 256, 0, stream>>>(
            xA, xP, hAg, hPg,
            x1A + (size_t)i * NA, x1P + (size_t)i * NP,
            w2A + (size_t)i * NA, w2P + (size_t)i * NP,
            h1Ac, h1Pc,
            cntA, slotsA, cntP, slotsP,
            a2nA_, a2nP_,
            hA[i & 1], hP[i & 1], h1Ab[i & 1], h1Pb[i & 1],
            nodes, FULL);
        hAg = hA[i & 1]; hPg = hP[i & 1];
        h1Ac = h1Ab[i & 1]; h1Pc = h1Pb[i & 1];
    }

    out_kernel<<<(NA + 63) / 64, 256, 0, stream>>>(hAg, W2, b2, out, NA);
}

// Round 11
// 437.258 us; speedup vs baseline: 1.5406x; 1.5406x over previous
//
#include <hip/hip_runtime.h>
#include <hip/hip_bf16.h>

#define HOPS 3
#define NA 50000
#define NP 100000
#define NIN 256
#define NHID 128
#define NOUT 64
#define CAP_A 64
#define CAP_P 40

typedef __attribute__((ext_vector_type(8))) short bf16x8;
typedef __attribute__((ext_vector_type(4))) float f32x4;
typedef unsigned short ushort_t;

__device__ inline short f2bf(float f) {
    __hip_bfloat16 h = __float2bfloat16(f);
    return *reinterpret_cast<short*>(&h);
}
__device__ inline float bf2f(unsigned short u) {
    unsigned v = ((unsigned)u) << 16;
    return __uint_as_float(v);
}

// async global -> LDS, 16 bytes per lane (linear dest: base + lane*16)
__device__ inline void gload16(const void* g, void* l) {
    __builtin_amdgcn_global_load_lds(
        (const __attribute__((address_space(1))) unsigned int*)g,
        (__attribute__((address_space(3))) unsigned int*)l, 16, 0, 0);
}

// ---------- weight transposes+converts + cnt zeroing (runs BEFORE fill) ----------
__global__ void prep_all(const float* __restrict__ W1_A, const float* __restrict__ W1_P,
                         const float* __restrict__ W2,
                         short* __restrict__ WtA, short* __restrict__ WtP,
                         short* __restrict__ Wt2,
                         int* __restrict__ cntA, int* __restrict__ cntP)
{
    int idx = blockIdx.x * 256 + threadIdx.x;
    const int S1 = NHID * NIN;
    const int SW = 2 * S1 + NOUT * NHID;
    if (idx < S1) {
        int n = idx / NIN, k = idx - n * NIN;
        WtA[idx] = f2bf(W1_A[(size_t)k * NHID + n]);
    } else if (idx < 2 * S1) {
        int j = idx - S1;
        int n = j / NIN, k = j - n * NIN;
        WtP[j] = f2bf(W1_P[(size_t)k * NHID + n]);
    } else if (idx < SW) {
        int j = idx - 2 * S1;
        int n = j / NHID, k = j - n * NHID;
        Wt2[j] = f2bf(W2[(size_t)k * NOUT + n]);
    } else if (idx < SW + NA) {
        cntA[idx - SW] = 0;
    } else if (idx < SW + NA + NP) {
        cntP[idx - SW - NA] = 0;
    }
}

// ---------- projection: R2 structure, W-LDS removed (B-frags direct from L2) ----------
// Cbf[M,128] = bf16(relu(A[M,256] @ W + b)). 256 thr / 4 waves, tile 64x128,
// BK=32, A-tile staged coalesced f32->bf16 in padded LDS; LDS only 5.1KB ->
// 8 blocks/CU occupancy. mfma 16x16x32: A row=l&15,k=(l>>4)*8+j ; B col=l&15 ;
// D col=l&15,row=(l>>4)*4+j
__global__ __launch_bounds__(256) void proj_mfma(const float* __restrict__ A,
                                                 const short* __restrict__ Wt,
                                                 const float* __restrict__ b,
                                                 ushort_t* __restrict__ Cbf, int M)
{
    __shared__ short Alds[64][40];   // stride 80B: 16B-aligned, 2-way-free banks
    int tid = threadIdx.x;
    int br = blockIdx.x * 64;
    int wv = tid >> 6;
    int l = tid & 63;
    int fl = l & 15;
    int kg = l >> 4;

    int sr = tid >> 2;            // 0..63 row
    int skp = (tid & 3) * 8;      // k-part 0/8/16/24
    int sgr = br + sr; if (sgr >= M) sgr = M - 1;

    f32x4 acc[8];
    #pragma unroll
    for (int c = 0; c < 8; ++c) acc[c] = (f32x4){0.f, 0.f, 0.f, 0.f};

    const short* wp0 = Wt + (size_t)fl * NIN + kg * 8;

    for (int k0 = 0; k0 < NIN; k0 += 32) {
        // stage A tile 64x32 (f32 -> bf16), coalesced
        const float4* ap = (const float4*)(A + (size_t)sgr * NIN + k0 + skp);
        float4 v0 = ap[0], v1 = ap[1];
        union { short s[8]; int4 v; } pk;
        pk.s[0] = f2bf(v0.x); pk.s[1] = f2bf(v0.y);
        pk.s[2] = f2bf(v0.z); pk.s[3] = f2bf(v0.w);
        pk.s[4] = f2bf(v1.x); pk.s[5] = f2bf(v1.y);
        pk.s[6] = f2bf(v1.z); pk.s[7] = f2bf(v1.w);
        *(int4*)&Alds[sr][skp] = pk.v;
        __syncthreads();

        bf16x8 afr = *(bf16x8*)&Alds[wv * 16 + fl][kg * 8];
        #pragma unroll
        for (int c = 0; c < 8; ++c) {
            bf16x8 bfr = *(const bf16x8*)(wp0 + (size_t)c * 16 * NIN + k0);
            acc[c] = __builtin_amdgcn_mfma_f32_16x16x32_bf16(afr, bfr, acc[c], 0, 0, 0);
        }
        __syncthreads();
    }

    int rj = kg * 4;
    #pragma unroll
    for (int c = 0; c < 8; ++c) {
        int col = c * 16 + fl;
        float bb = b[col];
        #pragma unroll
        for (int j = 0; j < 4; ++j) {
            int grow = br + wv * 16 + rj + j;
            if (grow < M) {
                float v = fmaxf(acc[c][j] + bb, 0.f);
                Cbf[(size_t)grow * NHID + col] = (ushort_t)f2bf(v);
            }
        }
    }
}

// ---------- output: C[M,64] = Abf[M,128] @ W2 + b2, single-stage MFMA ----------
__global__ __launch_bounds__(256) void out_mfma(const ushort_t* __restrict__ Abf,
        const short* __restrict__ Wt, const float* __restrict__ b,
        float* __restrict__ C, int M)
{
    __shared__ ushort_t Sb[64 * 128];
    const int tid = threadIdx.x;
    const int wv = tid >> 6, l = tid & 63;
    const int fl = l & 15, kg = l >> 4;
    const int br = blockIdx.x * 64;
    const int srow = l >> 4, schk = l & 15;

    #pragma unroll
    for (int i = 0; i < 4; ++i) {
        int r = (wv * 4 + i) * 4 + srow;
        int gr = br + r; if (gr >= M) gr = M - 1;
        int ck = (schk ^ (r & 7)) * 8;
        gload16(Abf + (size_t)gr * NHID + ck, &Sb[(wv * 4 + i) * 512]);
    }

    f32x4 acc[4];
    #pragma unroll
    for (int c = 0; c < 4; ++c) acc[c] = (f32x4){0.f, 0.f, 0.f, 0.f};

    bf16x8 Bf[16];
    #pragma unroll
    for (int ks = 0; ks < 4; ++ks)
        #pragma unroll
        for (int cc = 0; cc < 4; ++cc)
            Bf[ks * 4 + cc] = *(const bf16x8*)(Wt + (size_t)(cc * 16 + fl) * NHID
                                               + ks * 32 + kg * 8);
    __syncthreads();

    const int R = wv * 16 + fl;
    const int rx = R & 7;
    #pragma unroll
    for (int ks = 0; ks < 4; ++ks) {
        int chunk = (ks * 4 + kg) ^ rx;
        bf16x8 af = *(const bf16x8*)&Sb[R * 128 + chunk * 8];
        #pragma unroll
        for (int cc = 0; cc < 4; ++cc)
            acc[cc] = __builtin_amdgcn_mfma_f32_16x16x32_bf16(af, Bf[ks * 4 + cc],
                                                              acc[cc], 0, 0, 0);
    }

    #pragma unroll
    for (int cc = 0; cc < 4; ++cc) {
        int col = cc * 16 + fl;
        float bb = b[col];
        #pragma unroll
        for (int j = 0; j < 4; ++j) {
            int grow = br + wv * 16 + kg * 4 + j;
            if (grow < M) C[(size_t)grow * NOUT + col] = acc[cc][j] + bb;
        }
    }
}

// ---------- merged padded-CSR fill ----------
__global__ void fill_kernel(const int* __restrict__ sA, const int* __restrict__ tA,
                            const int* __restrict__ sP, const int* __restrict__ tP,
                            int* __restrict__ cntA, int* __restrict__ slotsA,
                            int* __restrict__ cntP, int* __restrict__ slotsP, int nE)
{
    int e = blockIdx.x * 256 + threadIdx.x;
    if (e < nE) {
        int si = sA[e];
        int c = atomicAdd(&cntA[si], 1);
        if (c < CAP_A) slotsA[(size_t)si * CAP_A + c] = tA[e];
    } else if (e < 2 * nE) {
        int k = e - nE;
        int si = sP[k];
        int c = atomicAdd(&cntP[si], 1);
        if (c < CAP_P) slotsP[(size_t)si * CAP_P + c] = tP[k];
    }
}

// ---------- merged x-side scalars for ALL hops ----------
__global__ void xdots_kernel(const ushort_t* __restrict__ xAbf, const ushort_t* __restrict__ xPbf,
                             const float* __restrict__ attn1, const float* __restrict__ attn2,
                             float* __restrict__ x1A, float* __restrict__ w2A, float* __restrict__ h1Ai,
                             float* __restrict__ x1P, float* __restrict__ w2P, float* __restrict__ h1Pi)
{
    int wid = (blockIdx.x * blockDim.x + threadIdx.x) >> 6;
    int lane = threadIdx.x & 63;
    if (wid >= NA + NP) return;
    bool isA = wid < NA;
    int n = isA ? wid : wid - NA;
    int etype = isA ? 0 : 1;
    const ushort_t* x = (isA ? xAbf : xPbf) + (size_t)n * NHID;
    ushort2 xv = *(const ushort2*)(x + lane * 2);
    float xa = bf2f(xv.x), xb = bf2f(xv.y);
    float s[7];
    #pragma unroll
    for (int i = 0; i < 3; ++i) {
        float2 a1v = *(const float2*)(attn1 + (size_t)(i * 2 + etype) * NHID + lane * 2);
        float2 a2v = *(const float2*)(attn2 + (size_t)(i * 2 + etype) * NHID + lane * 2);
        s[i]     = xa * a1v.x + xb * a1v.y;
        s[3 + i] = xa * a2v.x + xb * a2v.y;
    }
    float2 a2o = *(const float2*)(attn2 + (size_t)(1 - etype) * NHID + lane * 2);
    s[6] = xa * a2o.x + xb * a2o.y;
    #pragma unroll
    for (int m = 32; m; m >>= 1)
        #pragma unroll
        for (int i = 0; i < 7; ++i) s[i] += __shfl_xor(s[i], m, 64);
    if (lane == 0) {
        int N = isA ? NA : NP;
        float* x1 = isA ? x1A : x1P;
        float* w2 = isA ? w2A : w2P;
        #pragma unroll
        for (int i = 0; i < 3; ++i) {
            x1[(size_t)i * N + n] = s[i];
            float v = s[i] + s[3 + i];
            v = v > 0.f ? v : 0.2f * v;
            w2[(size_t)i * N + n] = __expf(v);
        }
        (isA ? h1Ai : h1Pi)[n] = s[6];
    }
}

// ---------- fused A+P aggregation: 16 feature-lanes x 4 edge-groups ----------
// Wave-cooperative preload of all (t,w); inner loop 1 int4 per lane per edge
// (fl owns 8 features); xor-butterfly leaves FULL sums in every lane, so the
// epilogue is split across groups: each lane finishes exactly 2 features.
__global__ __launch_bounds__(256) void agg_fused(
    const ushort_t* __restrict__ xAbf, const ushort_t* __restrict__ xPbf,
    const ushort_t* __restrict__ hAg, const ushort_t* __restrict__ hPg,
    const float* __restrict__ x1Ah, const float* __restrict__ x1Ph,
    const float* __restrict__ w2Ah, const float* __restrict__ w2Ph,
    const float* __restrict__ h1Agc, const float* __restrict__ h1Pgc,
    const int* __restrict__ cntA, const int* __restrict__ slotsA,
    const int* __restrict__ cntP, const int* __restrict__ slotsP,
    const float* __restrict__ a2nA, const float* __restrict__ a2nP,
    ushort_t* __restrict__ hAout, ushort_t* __restrict__ hPout,
    float* __restrict__ h1Aout, float* __restrict__ h1Pout,
    int nodes)
{
    int wid = (blockIdx.x * blockDim.x + threadIdx.x) >> 6;
    int lane = threadIdx.x & 63;
    if (wid >= nodes) return;
    int g = lane >> 4, fl = lane & 15;
    bool isA = wid < NA;
    int n = isA ? wid : wid - NA;
    int deg; const int* sl; const ushort_t* hbf; const float* h1g; float x1v;
    if (isA) {
        deg = cntA[n]; if (deg > CAP_A) deg = CAP_A;
        sl = slotsA + (size_t)n * CAP_A; hbf = hPg; h1g = h1Pgc; x1v = x1Ah[n];
    } else {
        deg = cntP[n]; if (deg > CAP_P) deg = CAP_P;
        sl = slotsP + (size_t)n * CAP_P; hbf = hAg; h1g = h1Agc; x1v = x1Ph[n];
    }

    // cooperative preload: lane l holds edge l's (t, w)
    int t_l = 0;
    float w_l = 0.f;
    if (deg > 0) {
        int idx = lane < deg ? lane : deg - 1;
        t_l = sl[idx];
        if (lane < deg) {
            float v = x1v + h1g[t_l];
            v = v > 0.f ? v : 0.2f * v;
            w_l = __expf(v);
        }
    }
    float div = w_l;
    #pragma unroll
    for (int m = 1; m <= 32; m <<= 1) div += __shfl_xor(div, m, 64);

    float acc[8] = {};
    int R = (deg + 3) >> 2;

    int4 ra = {0, 0, 0, 0};
    if (R > 0) {
        int t0 = __shfl(t_l, g, 64);
        ra = *(const int4*)(hbf + (size_t)t0 * NHID + fl * 8);
    }
    for (int r = 0; r < R; ++r) {
        float w = __shfl(w_l, r * 4 + g, 64);
        int4 cur = ra;
        if (r + 1 < R) {
            int tn = __shfl(t_l, (r + 1) * 4 + g, 64);
            ra = *(const int4*)(hbf + (size_t)tn * NHID + fl * 8);
        }
        unsigned q0 = (unsigned)cur.x, q1 = (unsigned)cur.y;
        unsigned q2 = (unsigned)cur.z, q3 = (unsigned)cur.w;
        acc[0] += w * __uint_as_float(q0 << 16);
        acc[1] += w * __uint_as_float(q0 & 0xffff0000u);
        acc[2] += w * __uint_as_float(q1 << 16);
        acc[3] += w * __uint_as_float(q1 & 0xffff0000u);
        acc[4] += w * __uint_as_float(q2 << 16);
        acc[5] += w * __uint_as_float(q2 & 0xffff0000u);
        acc[6] += w * __uint_as_float(q3 << 16);
        acc[7] += w * __uint_as_float(q3 & 0xffff0000u);
    }
    // combine the 4 groups; afterwards EVERY lane holds full sums for its fl
    #pragma unroll
    for (int m = 16; m <= 32; m <<= 1) {
        #pragma unroll
        for (int j = 0; j < 8; ++j) acc[j] += __shfl_xor(acc[j], m, 64);
    }

    // all-lane epilogue: lane (g,fl) finishes features fl*8 + 2g, 2g+1
    float alo = (g == 0) ? acc[0] : (g == 1) ? acc[2] : (g == 2) ? acc[4] : acc[6];
    float ahi = (g == 0) ? acc[1] : (g == 1) ? acc[3] : (g == 2) ? acc[5] : acc[7];

    float w2v = isA ? w2Ah[n] : w2Ph[n];
    const ushort_t* xb = (isA ? xAbf : xPbf) + (size_t)n * NHID;
    unsigned xq = *(const unsigned*)(xb + fl * 8 + 2 * g);
    alo += w2v * __uint_as_float(xq << 16);
    ahi += w2v * __uint_as_float(xq & 0xffff0000u);
    float dv = div + w2v;
    float inv = 1.f / dv;
    float vlo = alo * inv, vhi = ahi * inv;
    float olo = vlo > 0.f ? vlo : (__expf(vlo) - 1.f);
    float ohi = vhi > 0.f ? vhi : (__expf(vhi) - 1.f);

    // next-hop h1 dot (full-wave)
    const float* a2 = isA ? a2nA : a2nP;
    float2 av = *(const float2*)(a2 + fl * 8 + 2 * g);
    float s = olo * av.x + ohi * av.y;
    #pragma unroll
    for (int m = 1; m <= 32; m <<= 1) s += __shfl_xor(s, m, 64);

    // packed store: one u32 (2 bf16) per lane = full 256B row per wave
    unsigned plo = ((unsigned)(ushort_t)f2bf(olo));
    unsigned phi = ((unsigned)(ushort_t)f2bf(ohi)) << 16;
    unsigned* hb = (unsigned*)((isA ? hAout : hPout) + (size_t)n * NHID);
    hb[fl * 4 + g] = plo | phi;
    if (lane == 0) (isA ? h1Aout : h1Pout)[n] = s;
}

extern "C" void kernel_launch(void* const* d_in, const int* in_sizes, int n_in,
                              void* d_out, int out_size, void* d_ws, size_t ws_size,
                              hipStream_t stream)
{
    const float* x_A  = (const float*)d_in[0];
    const float* x_P  = (const float*)d_in[1];
    const int*   sAP  = (const int*)d_in[2];
    const int*   tAP  = (const int*)d_in[3];
    const int*   sPA  = (const int*)d_in[4];
    const int*   tPA  = (const int*)d_in[5];
    const float* W1_A = (const float*)d_in[6];
    const float* b1_A = (const float*)d_in[7];
    const float* W1_P = (const float*)d_in[8];
    const float* b1_P = (const float*)d_in[9];
    const float* attn1 = (const float*)d_in[10];
    const float* attn2 = (const float*)d_in[11];
    const float* W2   = (const float*)d_in[12];
    const float* b2   = (const float*)d_in[13];
    float* out = (float*)d_out;
    int nE = in_sizes[2];

    char* ws = (char*)d_ws;
    size_t off = 0;
    auto alloc = [&](size_t bytes) -> void* {
        void* p = ws + off;
        off += (bytes + 255) & ~(size_t)255;
        return p;
    };
    ushort_t* xAbf  = (ushort_t*)alloc((size_t)NA * NHID * 2);
    ushort_t* xPbf  = (ushort_t*)alloc((size_t)NP * NHID * 2);
    ushort_t* hAbf[2] = {(ushort_t*)alloc((size_t)NA * NHID * 2),
                         (ushort_t*)alloc((size_t)NA * NHID * 2)};
    ushort_t* hPbf[2] = {(ushort_t*)alloc((size_t)NP * NHID * 2),
                         (ushort_t*)alloc((size_t)NP * NHID * 2)};
    float* x1A = (float*)alloc((size_t)3 * NA * 4);
    float* w2A = (float*)alloc((size_t)3 * NA * 4);
    float* x1P = (float*)alloc((size_t)3 * NP * 4);
    float* w2P = (float*)alloc((size_t)3 * NP * 4);
    float* h1Ai = (float*)alloc(NA * 4);
    float* h1Pi = (float*)alloc(NP * 4);
    float* h1Ab[2] = {(float*)alloc(NA * 4), (float*)alloc(NA * 4)};
    float* h1Pb[2] = {(float*)alloc(NP * 4), (float*)alloc(NP * 4)};
    int* cntA  = (int*)alloc(NA * 4);
    int* cntP  = (int*)alloc(NP * 4);
    int* slotsA = (int*)alloc((size_t)NA * CAP_A * 4);
    int* slotsP = (int*)alloc((size_t)NP * CAP_P * 4);
    short* WtA = (short*)alloc((size_t)NHID * NIN * 2);
    short* WtP = (short*)alloc((size_t)NHID * NIN * 2);
    short* Wt2 = (short*)alloc((size_t)NOUT * NHID * 2);

    // weights -> bf16 transposed + cnt zeroing (before fill)
    int prepN = 2 * NHID * NIN + NOUT * NHID + NA + NP;
    prep_all<<<(prepN + 255) / 256, 256, 0, stream>>>(W1_A, W1_P, W2, WtA, WtP, Wt2,
                                                      cntA, cntP);

    // padded CSR (edge structure reused by all hops)
    fill_kernel<<<(2 * nE + 255) / 256, 256, 0, stream>>>(sAP, tAP, sPA, tPA,
                                                          cntA, slotsA, cntP, slotsP, nE);

    // projections -> bf16 h0
    proj_mfma<<<(NA + 63) / 64, 256, 0, stream>>>(x_A, WtA, b1_A, xAbf, NA);
    proj_mfma<<<(NP + 63) / 64, 256, 0, stream>>>(x_P, WtP, b1_P, xPbf, NP);

    // x-side scalars for all hops (merged)
    xdots_kernel<<<(NA + NP + 3) / 4, 256, 0, stream>>>(
        xAbf, xPbf, attn1, attn2, x1A, w2A, h1Ai, x1P, w2P, h1Pi);

    const ushort_t* hAg = xAbf;
    const ushort_t* hPg = xPbf;
    const float* h1Ac = h1Ai;
    const float* h1Pc = h1Pi;

    for (int i = 0; i < HOPS; ++i) {
        int last = (i == HOPS - 1);
        int nodes = last ? NA : (NA + NP);
        const float* a2nA_ = last ? attn2 : attn2 + (size_t)((i + 1) * 2 + 1) * NHID;
        const float* a2nP_ = last ? attn2 : attn2 + (size_t)((i + 1) * 2 + 0) * NHID;
        agg_fused<<<(nodes + 3) / 4, 256, 0, stream>>>(
            xAbf, xPbf, hAg, hPg,
            x1A + (size_t)i * NA, x1P + (size_t)i * NP,
            w2A + (size_t)i * NA, w2P + (size_t)i * NP,
            h1Ac, h1Pc,
            cntA, slotsA, cntP, slotsP,
            a2nA_, a2nP_,
            hAbf[i & 1], hPbf[i & 1], h1Ab[i & 1], h1Pb[i & 1],
            nodes);
        hAg = hAbf[i & 1]; hPg = hPbf[i & 1];
        h1Ac = h1Ab[i & 1]; h1Pc = h1Pb[i & 1];
    }

    out_mfma<<<(NA + 63) / 64, 256, 0, stream>>>(hAg, Wt2, b2, out, NA);
}

// Round 12
// 391.023 us; speedup vs baseline: 1.7228x; 1.1182x over previous
//
#include <hip/hip_runtime.h>
#include <hip/hip_bf16.h>
#include <hip/hip_fp16.h>

#define HOPS 3
#define NA 50000
#define NP 100000
#define NIN 256
#define NHID 128
#define NOUT 64
#define CAP_A 64
#define CAP_P 40

typedef _Float16 half_t;
typedef __attribute__((ext_vector_type(8))) _Float16 f16x8;
typedef __attribute__((ext_vector_type(4))) float f32x4;
typedef unsigned short ushort_t;

// async global -> LDS, 16 bytes per lane (linear dest: base + lane*16)
__device__ inline void gload16(const void* g, void* l) {
    __builtin_amdgcn_global_load_lds(
        (const __attribute__((address_space(1))) unsigned int*)g,
        (__attribute__((address_space(3))) unsigned int*)l, 16, 0, 0);
}

// ---------- weight transposes+converts (f16) + cnt zeroing (runs BEFORE fill) ----------
__global__ void prep_all(const float* __restrict__ W1_A, const float* __restrict__ W1_P,
                         const float* __restrict__ W2,
                         half_t* __restrict__ WtA, half_t* __restrict__ WtP,
                         half_t* __restrict__ Wt2,
                         int* __restrict__ cntA, int* __restrict__ cntP)
{
    int idx = blockIdx.x * 256 + threadIdx.x;
    const int S1 = NHID * NIN;
    const int SW = 2 * S1 + NOUT * NHID;
    if (idx < S1) {
        int n = idx / NIN, k = idx - n * NIN;
        WtA[idx] = (half_t)W1_A[(size_t)k * NHID + n];
    } else if (idx < 2 * S1) {
        int j = idx - S1;
        int n = j / NIN, k = j - n * NIN;
        WtP[j] = (half_t)W1_P[(size_t)k * NHID + n];
    } else if (idx < SW) {
        int j = idx - 2 * S1;
        int n = j / NHID, k = j - n * NHID;
        Wt2[j] = (half_t)W2[(size_t)k * NOUT + n];
    } else if (idx < SW + NA) {
        cntA[idx - SW] = 0;
    } else if (idx < SW + NA + NP) {
        cntP[idx - SW - NA] = 0;
    }
}

// ---------- projection (R2/R9 measured-best structure, f16) ----------
// Chf[M,128] = f16(relu(A[M,256] @ W + b)). 256 thr / 4 waves, tile 64x128,
// BK=32, BOTH A-tile (f32->f16 at stage) and Wt-tile staged in padded LDS
// (stride 40 halves), 2 barriers per K-step.
// mfma_f32_16x16x32_f16: A row=l&15,k=(l>>4)*8+j ; B col=l&15 ; D col=l&15,row=(l>>4)*4+j
__global__ __launch_bounds__(256) void proj_mfma(const float* __restrict__ A,
                                                 const half_t* __restrict__ Wt,
                                                 const float* __restrict__ b,
                                                 half_t* __restrict__ Chf, int M)
{
    __shared__ half_t Alds[64][40];    // stride 80B: 16B-aligned, 2-way-free banks
    __shared__ half_t Wlds[128][40];
    int tid = threadIdx.x;
    int br = blockIdx.x * 64;
    int wv = tid >> 6;
    int l = tid & 63;
    int fl = l & 15;
    int kg = l >> 4;

    int sr = tid >> 2;            // 0..63 row
    int skp = (tid & 3) * 8;      // k-part 0/8/16/24
    int sgr = br + sr; if (sgr >= M) sgr = M - 1;
    int sn = tid >> 1;            // 0..127 col of Wt
    int skq = (tid & 1) * 16;     // 0/16

    f32x4 acc[8];
    #pragma unroll
    for (int c = 0; c < 8; ++c) acc[c] = (f32x4){0.f, 0.f, 0.f, 0.f};

    for (int k0 = 0; k0 < NIN; k0 += 32) {
        // stage A tile 64x32 (f32 -> f16)
        const float4* ap = (const float4*)(A + (size_t)sgr * NIN + k0 + skp);
        float4 v0 = ap[0], v1 = ap[1];
        union { half_t s[8]; int4 v; } pk;
        pk.s[0] = (half_t)v0.x; pk.s[1] = (half_t)v0.y;
        pk.s[2] = (half_t)v0.z; pk.s[3] = (half_t)v0.w;
        pk.s[4] = (half_t)v1.x; pk.s[5] = (half_t)v1.y;
        pk.s[6] = (half_t)v1.z; pk.s[7] = (half_t)v1.w;
        *(int4*)&Alds[sr][skp] = pk.v;
        // stage Wt tile 128x32 (f16 copy)
        const int4* wp = (const int4*)(Wt + (size_t)sn * NIN + k0 + skq);
        int4 w0 = wp[0], w1 = wp[1];
        *(int4*)&Wlds[sn][skq] = w0;
        *(int4*)&Wlds[sn][skq + 8] = w1;
        __syncthreads();

        f16x8 afr = *(f16x8*)&Alds[wv * 16 + fl][kg * 8];
        #pragma unroll
        for (int c = 0; c < 8; ++c) {
            f16x8 bfr = *(f16x8*)&Wlds[c * 16 + fl][kg * 8];
            acc[c] = __builtin_amdgcn_mfma_f32_16x16x32_f16(afr, bfr, acc[c], 0, 0, 0);
        }
        __syncthreads();
    }

    int rj = kg * 4;
    #pragma unroll
    for (int c = 0; c < 8; ++c) {
        int col = c * 16 + fl;
        float bb = b[col];
        #pragma unroll
        for (int j = 0; j < 4; ++j) {
            int grow = br + wv * 16 + rj + j;
            if (grow < M) {
                float v = fmaxf(acc[c][j] + bb, 0.f);
                Chf[(size_t)grow * NHID + col] = (half_t)v;
            }
        }
    }
}

// ---------- output: C[M,64] = Ahf[M,128] @ W2 + b2, single-stage f16 MFMA ----------
__global__ __launch_bounds__(256) void out_mfma(const half_t* __restrict__ Ahf,
        const half_t* __restrict__ Wt, const float* __restrict__ b,
        float* __restrict__ C, int M)
{
    __shared__ half_t Sb[64 * 128];   // 16KB
    const int tid = threadIdx.x;
    const int wv = tid >> 6, l = tid & 63;
    const int fl = l & 15, kg = l >> 4;
    const int br = blockIdx.x * 64;
    const int srow = l >> 4, schk = l & 15;

    #pragma unroll
    for (int i = 0; i < 4; ++i) {
        int r = (wv * 4 + i) * 4 + srow;
        int gr = br + r; if (gr >= M) gr = M - 1;
        int ck = (schk ^ (r & 7)) * 8;
        gload16(Ahf + (size_t)gr * NHID + ck, &Sb[(wv * 4 + i) * 512]);
    }

    f32x4 acc[4];
    #pragma unroll
    for (int c = 0; c < 4; ++c) acc[c] = (f32x4){0.f, 0.f, 0.f, 0.f};

    f16x8 Bf[16];
    #pragma unroll
    for (int ks = 0; ks < 4; ++ks)
        #pragma unroll
        for (int cc = 0; cc < 4; ++cc)
            Bf[ks * 4 + cc] = *(const f16x8*)(Wt + (size_t)(cc * 16 + fl) * NHID
                                              + ks * 32 + kg * 8);
    __syncthreads();

    const int R = wv * 16 + fl;
    const int rx = R & 7;
    #pragma unroll
    for (int ks = 0; ks < 4; ++ks) {
        int chunk = (ks * 4 + kg) ^ rx;
        f16x8 af = *(const f16x8*)&Sb[R * 128 + chunk * 8];
        #pragma unroll
        for (int cc = 0; cc < 4; ++cc)
            acc[cc] = __builtin_amdgcn_mfma_f32_16x16x32_f16(af, Bf[ks * 4 + cc],
                                                             acc[cc], 0, 0, 0);
    }

    #pragma unroll
    for (int cc = 0; cc < 4; ++cc) {
        int col = cc * 16 + fl;
        float bb = b[col];
        #pragma unroll
        for (int j = 0; j < 4; ++j) {
            int grow = br + wv * 16 + kg * 4 + j;
            if (grow < M) C[(size_t)grow * NOUT + col] = acc[cc][j] + bb;
        }
    }
}

// ---------- merged padded-CSR fill ----------
__global__ void fill_kernel(const int* __restrict__ sA, const int* __restrict__ tA,
                            const int* __restrict__ sP, const int* __restrict__ tP,
                            int* __restrict__ cntA, int* __restrict__ slotsA,
                            int* __restrict__ cntP, int* __restrict__ slotsP, int nE)
{
    int e = blockIdx.x * 256 + threadIdx.x;
    if (e < nE) {
        int si = sA[e];
        int c = atomicAdd(&cntA[si], 1);
        if (c < CAP_A) slotsA[(size_t)si * CAP_A + c] = tA[e];
    } else if (e < 2 * nE) {
        int k = e - nE;
        int si = sP[k];
        int c = atomicAdd(&cntP[si], 1);
        if (c < CAP_P) slotsP[(size_t)si * CAP_P + c] = tP[k];
    }
}

// ---------- merged x-side scalars for ALL hops (f16 x) ----------
__global__ void xdots_kernel(const half_t* __restrict__ xAh, const half_t* __restrict__ xPh,
                             const float* __restrict__ attn1, const float* __restrict__ attn2,
                             float* __restrict__ x1A, float* __restrict__ w2A, float* __restrict__ h1Ai,
                             float* __restrict__ x1P, float* __restrict__ w2P, float* __restrict__ h1Pi)
{
    int wid = (blockIdx.x * blockDim.x + threadIdx.x) >> 6;
    int lane = threadIdx.x & 63;
    if (wid >= NA + NP) return;
    bool isA = wid < NA;
    int n = isA ? wid : wid - NA;
    int etype = isA ? 0 : 1;
    const half_t* x = (isA ? xAh : xPh) + (size_t)n * NHID;
    union { unsigned u; half_t h[2]; } xc;
    xc.u = *(const unsigned*)(x + lane * 2);
    float xa = (float)xc.h[0], xb = (float)xc.h[1];
    float s[7];
    #pragma unroll
    for (int i = 0; i < 3; ++i) {
        float2 a1v = *(const float2*)(attn1 + (size_t)(i * 2 + etype) * NHID + lane * 2);
        float2 a2v = *(const float2*)(attn2 + (size_t)(i * 2 + etype) * NHID + lane * 2);
        s[i]     = xa * a1v.x + xb * a1v.y;
        s[3 + i] = xa * a2v.x + xb * a2v.y;
    }
    float2 a2o = *(const float2*)(attn2 + (size_t)(1 - etype) * NHID + lane * 2);
    s[6] = xa * a2o.x + xb * a2o.y;
    #pragma unroll
    for (int m = 32; m; m >>= 1)
        #pragma unroll
        for (int i = 0; i < 7; ++i) s[i] += __shfl_xor(s[i], m, 64);
    if (lane == 0) {
        int N = isA ? NA : NP;
        float* x1 = isA ? x1A : x1P;
        float* w2 = isA ? w2A : w2P;
        #pragma unroll
        for (int i = 0; i < 3; ++i) {
            x1[(size_t)i * N + n] = s[i];
            float v = s[i] + s[3 + i];
            v = v > 0.f ? v : 0.2f * v;
            w2[(size_t)i * N + n] = __expf(v);
        }
        (isA ? h1Ai : h1Pi)[n] = s[6];
    }
}

// ---------- fused A+P aggregation: 16 feature-lanes x 4 edge-groups, f16 h ----------
// Wave-cooperative preload of all (t,w); inner loop 1 int4 per lane per edge
// (fl owns 8 f16 features); fmaf(w,(float)h16,acc) -> v_fma_mix_f32 (no unpack).
// xor-butterfly leaves FULL sums in every lane; epilogue split across groups.
__global__ __launch_bounds__(256) void agg_fused(
    const half_t* __restrict__ xAh, const half_t* __restrict__ xPh,
    const half_t* __restrict__ hAg, const half_t* __restrict__ hPg,
    const float* __restrict__ x1Ah, const float* __restrict__ x1Ph,
    const float* __restrict__ w2Ah, const float* __restrict__ w2Ph,
    const float* __restrict__ h1Agc, const float* __restrict__ h1Pgc,
    const int* __restrict__ cntA, const int* __restrict__ slotsA,
    const int* __restrict__ cntP, const int* __restrict__ slotsP,
    const float* __restrict__ a2nA, const float* __restrict__ a2nP,
    half_t* __restrict__ hAout, half_t* __restrict__ hPout,
    float* __restrict__ h1Aout, float* __restrict__ h1Pout,
    int nodes)
{
    int wid = (blockIdx.x * blockDim.x + threadIdx.x) >> 6;
    int lane = threadIdx.x & 63;
    if (wid >= nodes) return;
    int g = lane >> 4, fl = lane & 15;
    bool isA = wid < NA;
    int n = isA ? wid : wid - NA;
    int deg; const int* sl; const half_t* hbf; const float* h1g; float x1v;
    if (isA) {
        deg = cntA[n]; if (deg > CAP_A) deg = CAP_A;
        sl = slotsA + (size_t)n * CAP_A; hbf = hPg; h1g = h1Pgc; x1v = x1Ah[n];
    } else {
        deg = cntP[n]; if (deg > CAP_P) deg = CAP_P;
        sl = slotsP + (size_t)n * CAP_P; hbf = hAg; h1g = h1Agc; x1v = x1Ph[n];
    }

    // cooperative preload: lane l holds edge l's (t, w)
    int t_l = 0;
    float w_l = 0.f;
    if (deg > 0) {
        int idx = lane < deg ? lane : deg - 1;
        t_l = sl[idx];
        if (lane < deg) {
            float v = x1v + h1g[t_l];
            v = v > 0.f ? v : 0.2f * v;
            w_l = __expf(v);
        }
    }
    float div = w_l;
    #pragma unroll
    for (int m = 1; m <= 32; m <<= 1) div += __shfl_xor(div, m, 64);

    float acc[8] = {};
    int R = (deg + 3) >> 2;

    int4 ra = {0, 0, 0, 0};
    if (R > 0) {
        int t0 = __shfl(t_l, g, 64);
        ra = *(const int4*)(hbf + (size_t)t0 * NHID + fl * 8);
    }
    for (int r = 0; r < R; ++r) {
        float w = __shfl(w_l, r * 4 + g, 64);
        union { int4 v; half_t h[8]; } cur;
        cur.v = ra;
        if (r + 1 < R) {
            int tn = __shfl(t_l, (r + 1) * 4 + g, 64);
            ra = *(const int4*)(hbf + (size_t)tn * NHID + fl * 8);
        }
        acc[0] = fmaf(w, (float)cur.h[0], acc[0]);
        acc[1] = fmaf(w, (float)cur.h[1], acc[1]);
        acc[2] = fmaf(w, (float)cur.h[2], acc[2]);
        acc[3] = fmaf(w, (float)cur.h[3], acc[3]);
        acc[4] = fmaf(w, (float)cur.h[4], acc[4]);
        acc[5] = fmaf(w, (float)cur.h[5], acc[5]);
        acc[6] = fmaf(w, (float)cur.h[6], acc[6]);
        acc[7] = fmaf(w, (float)cur.h[7], acc[7]);
    }
    // combine the 4 groups; afterwards EVERY lane holds full sums for its fl
    #pragma unroll
    for (int m = 16; m <= 32; m <<= 1) {
        #pragma unroll
        for (int j = 0; j < 8; ++j) acc[j] += __shfl_xor(acc[j], m, 64);
    }

    // all-lane epilogue: lane (g,fl) finishes features fl*8 + 2g, 2g+1
    float alo = (g == 0) ? acc[0] : (g == 1) ? acc[2] : (g == 2) ? acc[4] : acc[6];
    float ahi = (g == 0) ? acc[1] : (g == 1) ? acc[3] : (g == 2) ? acc[5] : acc[7];

    float w2v = isA ? w2Ah[n] : w2Ph[n];
    const half_t* xb = (isA ? xAh : xPh) + (size_t)n * NHID;
    union { unsigned u; half_t h[2]; } xc;
    xc.u = *(const unsigned*)(xb + fl * 8 + 2 * g);
    alo = fmaf(w2v, (float)xc.h[0], alo);
    ahi = fmaf(w2v, (float)xc.h[1], ahi);
    float dv = div + w2v;
    float inv = 1.f / dv;
    float vlo = alo * inv, vhi = ahi * inv;
    float olo = vlo > 0.f ? vlo : (__expf(vlo) - 1.f);
    float ohi = vhi > 0.f ? vhi : (__expf(vhi) - 1.f);

    // next-hop h1 dot (full-wave)
    const float* a2 = isA ? a2nA : a2nP;
    float2 av = *(const float2*)(a2 + fl * 8 + 2 * g);
    float s = olo * av.x + ohi * av.y;
    #pragma unroll
    for (int m = 1; m <= 32; m <<= 1) s += __shfl_xor(s, m, 64);

    // packed store: one u32 (2 f16) per lane = full 256B row per wave
    union { half_t h[2]; unsigned u; } pk2;
    pk2.h[0] = (half_t)olo;
    pk2.h[1] = (half_t)ohi;
    unsigned* hb = (unsigned*)((isA ? hAout : hPout) + (size_t)n * NHID);
    hb[fl * 4 + g] = pk2.u;
    if (lane == 0) (isA ? h1Aout : h1Pout)[n] = s;
}

extern "C" void kernel_launch(void* const* d_in, const int* in_sizes, int n_in,
                              void* d_out, int out_size, void* d_ws, size_t ws_size,
                              hipStream_t stream)
{
    const float* x_A  = (const float*)d_in[0];
    const float* x_P  = (const float*)d_in[1];
    const int*   sAP  = (const int*)d_in[2];
    const int*   tAP  = (const int*)d_in[3];
    const int*   sPA  = (const int*)d_in[4];
    const int*   tPA  = (const int*)d_in[5];
    const float* W1_A = (const float*)d_in[6];
    const float* b1_A = (const float*)d_in[7];
    const float* W1_P = (const float*)d_in[8];
    const float* b1_P = (const float*)d_in[9];
    const float* attn1 = (const float*)d_in[10];
    const float* attn2 = (const float*)d_in[11];
    const float* W2   = (const float*)d_in[12];
    const float* b2   = (const float*)d_in[13];
    float* out = (float*)d_out;
    int nE = in_sizes[2];

    char* ws = (char*)d_ws;
    size_t off = 0;
    auto alloc = [&](size_t bytes) -> void* {
        void* p = ws + off;
        off += (bytes + 255) & ~(size_t)255;
        return p;
    };
    half_t* xAh  = (half_t*)alloc((size_t)NA * NHID * 2);
    half_t* xPh  = (half_t*)alloc((size_t)NP * NHID * 2);
    half_t* hAh[2] = {(half_t*)alloc((size_t)NA * NHID * 2),
                      (half_t*)alloc((size_t)NA * NHID * 2)};
    half_t* hPh[2] = {(half_t*)alloc((size_t)NP * NHID * 2),
                      (half_t*)alloc((size_t)NP * NHID * 2)};
    float* x1A = (float*)alloc((size_t)3 * NA * 4);
    float* w2A = (float*)alloc((size_t)3 * NA * 4);
    float* x1P = (float*)alloc((size_t)3 * NP * 4);
    float* w2P = (float*)alloc((size_t)3 * NP * 4);
    float* h1Ai = (float*)alloc(NA * 4);
    float* h1Pi = (float*)alloc(NP * 4);
    float* h1Ab[2] = {(float*)alloc(NA * 4), (float*)alloc(NA * 4)};
    float* h1Pb[2] = {(float*)alloc(NP * 4), (float*)alloc(NP * 4)};
    int* cntA  = (int*)alloc(NA * 4);
    int* cntP  = (int*)alloc(NP * 4);
    int* slotsA = (int*)alloc((size_t)NA * CAP_A * 4);
    int* slotsP = (int*)alloc((size_t)NP * CAP_P * 4);
    half_t* WtA = (half_t*)alloc((size_t)NHID * NIN * 2);
    half_t* WtP = (half_t*)alloc((size_t)NHID * NIN * 2);
    half_t* Wt2 = (half_t*)alloc((size_t)NOUT * NHID * 2);

    // weights -> f16 transposed + cnt zeroing (before fill)
    int prepN = 2 * NHID * NIN + NOUT * NHID + NA + NP;
    prep_all<<<(prepN + 255) / 256, 256, 0, stream>>>(W1_A, W1_P, W2, WtA, WtP, Wt2,
                                                      cntA, cntP);

    // padded CSR (edge structure reused by all hops)
    fill_kernel<<<(2 * nE + 255) / 256, 256, 0, stream>>>(sAP, tAP, sPA, tPA,
                                                          cntA, slotsA, cntP, slotsP, nE);

    // projections -> f16 h0
    proj_mfma<<<(NA + 63) / 64, 256, 0, stream>>>(x_A, WtA, b1_A, xAh, NA);
    proj_mfma<<<(NP + 63) / 64, 256, 0, stream>>>(x_P, WtP, b1_P, xPh, NP);

    // x-side scalars for all hops (merged)
    xdots_kernel<<<(NA + NP + 3) / 4, 256, 0, stream>>>(
        xAh, xPh, attn1, attn2, x1A, w2A, h1Ai, x1P, w2P, h1Pi);

    const half_t* hAg = xAh;
    const half_t* hPg = xPh;
    const float* h1Ac = h1Ai;
    const float* h1Pc = h1Pi;

    for (int i = 0; i < HOPS; ++i) {
        int last = (i == HOPS - 1);
        int nodes = last ? NA : (NA + NP);
        const float* a2nA_ = last ? attn2 : attn2 + (size_t)((i + 1) * 2 + 1) * NHID;
        const float* a2nP_ = last ? attn2 : attn2 + (size_t)((i + 1) * 2 + 0) * NHID;
        agg_fused<<<(nodes + 3) / 4, 256, 0, stream>>>(
            xAh, xPh, hAg, hPg,
            x1A + (size_t)i * NA, x1P + (size_t)i * NP,
            w2A + (size_t)i * NA, w2P + (size_t)i * NP,
            h1Ac, h1Pc,
            cntA, slotsA, cntP, slotsP,
            a2nA_, a2nP_,
            hAh[i & 1], hPh[i & 1], h1Ab[i & 1], h1Pb[i & 1],
            nodes);
        hAg = hAh[i & 1]; hPg = hPh[i & 1];
        h1Ac = h1Ab[i & 1]; h1Pc = h1Pb[i & 1];
    }

    out_mfma<<<(NA + 63) / 64, 256, 0, stream>>>(hAg, Wt2, b2, out, NA);
}

// Round 13
// 340.876 us; speedup vs baseline: 1.9762x; 1.1471x over previous
//
#include <hip/hip_runtime.h>
#include <hip/hip_bf16.h>
#include <hip/hip_fp16.h>

#define HOPS 3
#define NA 50000
#define NP 100000
#define NIN 256
#define NHID 128
#define NOUT 64
#define CAP_A 64
#define CAP_P 40

typedef _Float16 half_t;
typedef __attribute__((ext_vector_type(8))) _Float16 f16x8;
typedef __attribute__((ext_vector_type(4))) float f32x4;
typedef unsigned short ushort_t;

// async global -> LDS, 16 bytes per lane (linear dest: base + lane*16)
__device__ inline void gload16(const void* g, void* l) {
    __builtin_amdgcn_global_load_lds(
        (const __attribute__((address_space(1))) unsigned int*)g,
        (__attribute__((address_space(3))) unsigned int*)l, 16, 0, 0);
}

// ---------- weight transposes+converts (f16) + cnt zeroing (runs BEFORE fill) ----------
__global__ void prep_all(const float* __restrict__ W1_A, const float* __restrict__ W1_P,
                         const float* __restrict__ W2,
                         half_t* __restrict__ WtA, half_t* __restrict__ WtP,
                         half_t* __restrict__ Wt2,
                         int* __restrict__ cntA, int* __restrict__ cntP)
{
    int idx = blockIdx.x * 256 + threadIdx.x;
    const int S1 = NHID * NIN;
    const int SW = 2 * S1 + NOUT * NHID;
    if (idx < S1) {
        int n = idx / NIN, k = idx - n * NIN;
        WtA[idx] = (half_t)W1_A[(size_t)k * NHID + n];
    } else if (idx < 2 * S1) {
        int j = idx - S1;
        int n = j / NIN, k = j - n * NIN;
        WtP[j] = (half_t)W1_P[(size_t)k * NHID + n];
    } else if (idx < SW) {
        int j = idx - 2 * S1;
        int n = j / NHID, k = j - n * NHID;
        Wt2[j] = (half_t)W2[(size_t)k * NOUT + n];
    } else if (idx < SW + NA) {
        cntA[idx - SW] = 0;
    } else if (idx < SW + NA + NP) {
        cntP[idx - SW - NA] = 0;
    }
}

// ---------- projection (R2/R9 measured-best structure, f16) ----------
__global__ __launch_bounds__(256) void proj_mfma(const float* __restrict__ A,
                                                 const half_t* __restrict__ Wt,
                                                 const float* __restrict__ b,
                                                 half_t* __restrict__ Chf, int M)
{
    __shared__ half_t Alds[64][40];
    __shared__ half_t Wlds[128][40];
    int tid = threadIdx.x;
    int br = blockIdx.x * 64;
    int wv = tid >> 6;
    int l = tid & 63;
    int fl = l & 15;
    int kg = l >> 4;

    int sr = tid >> 2;
    int skp = (tid & 3) * 8;
    int sgr = br + sr; if (sgr >= M) sgr = M - 1;
    int sn = tid >> 1;
    int skq = (tid & 1) * 16;

    f32x4 acc[8];
    #pragma unroll
    for (int c = 0; c < 8; ++c) acc[c] = (f32x4){0.f, 0.f, 0.f, 0.f};

    for (int k0 = 0; k0 < NIN; k0 += 32) {
        const float4* ap = (const float4*)(A + (size_t)sgr * NIN + k0 + skp);
        float4 v0 = ap[0], v1 = ap[1];
        union { half_t s[8]; int4 v; } pk;
        pk.s[0] = (half_t)v0.x; pk.s[1] = (half_t)v0.y;
        pk.s[2] = (half_t)v0.z; pk.s[3] = (half_t)v0.w;
        pk.s[4] = (half_t)v1.x; pk.s[5] = (half_t)v1.y;
        pk.s[6] = (half_t)v1.z; pk.s[7] = (half_t)v1.w;
        *(int4*)&Alds[sr][skp] = pk.v;
        const int4* wp = (const int4*)(Wt + (size_t)sn * NIN + k0 + skq);
        int4 w0 = wp[0], w1 = wp[1];
        *(int4*)&Wlds[sn][skq] = w0;
        *(int4*)&Wlds[sn][skq + 8] = w1;
        __syncthreads();

        f16x8 afr = *(f16x8*)&Alds[wv * 16 + fl][kg * 8];
        #pragma unroll
        for (int c = 0; c < 8; ++c) {
            f16x8 bfr = *(f16x8*)&Wlds[c * 16 + fl][kg * 8];
            acc[c] = __builtin_amdgcn_mfma_f32_16x16x32_f16(afr, bfr, acc[c], 0, 0, 0);
        }
        __syncthreads();
    }

    int rj = kg * 4;
    #pragma unroll
    for (int c = 0; c < 8; ++c) {
        int col = c * 16 + fl;
        float bb = b[col];
        #pragma unroll
        for (int j = 0; j < 4; ++j) {
            int grow = br + wv * 16 + rj + j;
            if (grow < M) {
                float v = fmaxf(acc[c][j] + bb, 0.f);
                Chf[(size_t)grow * NHID + col] = (half_t)v;
            }
        }
    }
}

// ---------- output: C[M,64] = Ahf[M,128] @ W2 + b2, single-stage f16 MFMA ----------
__global__ __launch_bounds__(256) void out_mfma(const half_t* __restrict__ Ahf,
        const half_t* __restrict__ Wt, const float* __restrict__ b,
        float* __restrict__ C, int M)
{
    __shared__ half_t Sb[64 * 128];
    const int tid = threadIdx.x;
    const int wv = tid >> 6, l = tid & 63;
    const int fl = l & 15, kg = l >> 4;
    const int br = blockIdx.x * 64;
    const int srow = l >> 4, schk = l & 15;

    #pragma unroll
    for (int i = 0; i < 4; ++i) {
        int r = (wv * 4 + i) * 4 + srow;
        int gr = br + r; if (gr >= M) gr = M - 1;
        int ck = (schk ^ (r & 7)) * 8;
        gload16(Ahf + (size_t)gr * NHID + ck, &Sb[(wv * 4 + i) * 512]);
    }

    f32x4 acc[4];
    #pragma unroll
    for (int c = 0; c < 4; ++c) acc[c] = (f32x4){0.f, 0.f, 0.f, 0.f};

    f16x8 Bf[16];
    #pragma unroll
    for (int ks = 0; ks < 4; ++ks)
        #pragma unroll
        for (int cc = 0; cc < 4; ++cc)
            Bf[ks * 4 + cc] = *(const f16x8*)(Wt + (size_t)(cc * 16 + fl) * NHID
                                              + ks * 32 + kg * 8);
    __syncthreads();

    const int R = wv * 16 + fl;
    const int rx = R & 7;
    #pragma unroll
    for (int ks = 0; ks < 4; ++ks) {
        int chunk = (ks * 4 + kg) ^ rx;
        f16x8 af = *(const f16x8*)&Sb[R * 128 + chunk * 8];
        #pragma unroll
        for (int cc = 0; cc < 4; ++cc)
            acc[cc] = __builtin_amdgcn_mfma_f32_16x16x32_f16(af, Bf[ks * 4 + cc],
                                                             acc[cc], 0, 0, 0);
    }

    #pragma unroll
    for (int cc = 0; cc < 4; ++cc) {
        int col = cc * 16 + fl;
        float bb = b[col];
        #pragma unroll
        for (int j = 0; j < 4; ++j) {
            int grow = br + wv * 16 + kg * 4 + j;
            if (grow < M) C[(size_t)grow * NOUT + col] = acc[cc][j] + bb;
        }
    }
}

// ---------- merged padded-CSR fill ----------
__global__ void fill_kernel(const int* __restrict__ sA, const int* __restrict__ tA,
                            const int* __restrict__ sP, const int* __restrict__ tP,
                            int* __restrict__ cntA, int* __restrict__ slotsA,
                            int* __restrict__ cntP, int* __restrict__ slotsP, int nE)
{
    int e = blockIdx.x * 256 + threadIdx.x;
    if (e < nE) {
        int si = sA[e];
        int c = atomicAdd(&cntA[si], 1);
        if (c < CAP_A) slotsA[(size_t)si * CAP_A + c] = tA[e];
    } else if (e < 2 * nE) {
        int k = e - nE;
        int si = sP[k];
        int c = atomicAdd(&cntP[si], 1);
        if (c < CAP_P) slotsP[(size_t)si * CAP_P + c] = tP[k];
    }
}

// ---------- merged x-side scalars for ALL hops (f16 x) ----------
__global__ void xdots_kernel(const half_t* __restrict__ xAh, const half_t* __restrict__ xPh,
                             const float* __restrict__ attn1, const float* __restrict__ attn2,
                             float* __restrict__ x1A, float* __restrict__ w2A, float* __restrict__ h1Ai,
                             float* __restrict__ x1P, float* __restrict__ w2P, float* __restrict__ h1Pi)
{
    int wid = (blockIdx.x * blockDim.x + threadIdx.x) >> 6;
    int lane = threadIdx.x & 63;
    if (wid >= NA + NP) return;
    bool isA = wid < NA;
    int n = isA ? wid : wid - NA;
    int etype = isA ? 0 : 1;
    const half_t* x = (isA ? xAh : xPh) + (size_t)n * NHID;
    union { unsigned u; half_t h[2]; } xc;
    xc.u = *(const unsigned*)(x + lane * 2);
    float xa = (float)xc.h[0], xb = (float)xc.h[1];
    float s[7];
    #pragma unroll
    for (int i = 0; i < 3; ++i) {
        float2 a1v = *(const float2*)(attn1 + (size_t)(i * 2 + etype) * NHID + lane * 2);
        float2 a2v = *(const float2*)(attn2 + (size_t)(i * 2 + etype) * NHID + lane * 2);
        s[i]     = xa * a1v.x + xb * a1v.y;
        s[3 + i] = xa * a2v.x + xb * a2v.y;
    }
    float2 a2o = *(const float2*)(attn2 + (size_t)(1 - etype) * NHID + lane * 2);
    s[6] = xa * a2o.x + xb * a2o.y;
    #pragma unroll
    for (int m = 32; m; m >>= 1)
        #pragma unroll
        for (int i = 0; i < 7; ++i) s[i] += __shfl_xor(s[i], m, 64);
    if (lane == 0) {
        int N = isA ? NA : NP;
        float* x1 = isA ? x1A : x1P;
        float* w2 = isA ? w2A : w2P;
        #pragma unroll
        for (int i = 0; i < 3; ++i) {
            x1[(size_t)i * N + n] = s[i];
            float v = s[i] + s[3 + i];
            v = v > 0.f ? v : 0.2f * v;
            w2[(size_t)i * N + n] = __expf(v);
        }
        (isA ? h1Ai : h1Pi)[n] = s[6];
    }
}

// ---------- fused A+P aggregation: 4 NODES PER WAVE, 16 lanes per node ----------
// Group g=lane>>4 owns node wid*4+g; each of its 16 lanes owns 8 f16 features
// and accumulates over ALL the node's edges serially -> acc butterflies gone;
// div / h1-dot reduce within 16 lanes (4 steps). (t,w) exchanged via per-wave
// LDS (within-wave RAW, no barrier). Row gathers prefetched 1 ahead.
__global__ __launch_bounds__(256) void agg_fused(
    const half_t* __restrict__ xAh, const half_t* __restrict__ xPh,
    const half_t* __restrict__ hAg, const half_t* __restrict__ hPg,
    const float* __restrict__ x1Ah, const float* __restrict__ x1Ph,
    const float* __restrict__ w2Ah, const float* __restrict__ w2Ph,
    const float* __restrict__ h1Agc, const float* __restrict__ h1Pgc,
    const int* __restrict__ cntA, const int* __restrict__ slotsA,
    const int* __restrict__ cntP, const int* __restrict__ slotsP,
    const float* __restrict__ a2nA, const float* __restrict__ a2nP,
    half_t* __restrict__ hAout, half_t* __restrict__ hPout,
    float* __restrict__ h1Aout, float* __restrict__ h1Pout,
    int nodes)
{
    __shared__ float2 ew[4][4][16];   // [wave][group][slot] : (t as bits, w)
    int tid = threadIdx.x;
    int wv = tid >> 6;
    int lane = tid & 63;
    int grp = lane >> 4, fl = lane & 15;
    int wid = (blockIdx.x * 256 + tid) >> 6;
    int ng = wid * 4 + grp;
    if (ng >= nodes) return;
    bool isA = ng < NA;
    int n = isA ? ng : ng - NA;
    int deg; const int* sl; const half_t* hbf; const float* h1g; float x1v;
    if (isA) {
        deg = cntA[n]; if (deg > CAP_A) deg = CAP_A;
        sl = slotsA + (size_t)n * CAP_A; hbf = hPg; h1g = h1Pgc; x1v = x1Ah[n];
    } else {
        deg = cntP[n]; if (deg > CAP_P) deg = CAP_P;
        sl = slotsP + (size_t)n * CAP_P; hbf = hAg; h1g = h1Agc; x1v = x1Ph[n];
    }

    float acc[8] = {};
    float divacc = 0.f;

    for (int c0 = 0; c0 < deg; c0 += 16) {
        // preload this chunk's (t, w): slot lane = fl
        int idx = c0 + fl;
        int tl = 0; float wl = 0.f;
        if (idx < deg) {
            tl = sl[idx];
            float v = x1v + h1g[tl];
            v = v > 0.f ? v : 0.2f * v;
            wl = __expf(v);
        }
        divacc += wl;
        ew[wv][grp][fl] = make_float2(__int_as_float(tl), wl);

        int rounds = deg - c0; if (rounds > 16) rounds = 16;
        float2 tw = ew[wv][grp][0];
        int4 ra = *(const int4*)(hbf + (size_t)__float_as_int(tw.x) * NHID + fl * 8);
        for (int j = 0; j < rounds; ++j) {
            float w = tw.y;
            union { int4 v; half_t h[8]; } cur;
            cur.v = ra;
            if (j + 1 < rounds) {
                tw = ew[wv][grp][j + 1];
                ra = *(const int4*)(hbf + (size_t)__float_as_int(tw.x) * NHID + fl * 8);
            }
            acc[0] = fmaf(w, (float)cur.h[0], acc[0]);
            acc[1] = fmaf(w, (float)cur.h[1], acc[1]);
            acc[2] = fmaf(w, (float)cur.h[2], acc[2]);
            acc[3] = fmaf(w, (float)cur.h[3], acc[3]);
            acc[4] = fmaf(w, (float)cur.h[4], acc[4]);
            acc[5] = fmaf(w, (float)cur.h[5], acc[5]);
            acc[6] = fmaf(w, (float)cur.h[6], acc[6]);
            acc[7] = fmaf(w, (float)cur.h[7], acc[7]);
        }
    }

    // div reduce within the 16-lane group
    #pragma unroll
    for (int m = 1; m <= 8; m <<= 1) divacc += __shfl_xor(divacc, m, 64);

    // self term + epilogue: each lane finishes its 8 features
    float w2v = isA ? w2Ah[n] : w2Ph[n];
    const half_t* xb = (isA ? xAh : xPh) + (size_t)n * NHID + fl * 8;
    union { int4 v; half_t h[8]; } xc;
    xc.v = *(const int4*)xb;
    #pragma unroll
    for (int j = 0; j < 8; ++j) acc[j] = fmaf(w2v, (float)xc.h[j], acc[j]);
    float dv = divacc + w2v;
    float inv = 1.f / dv;

    const float* a2 = isA ? a2nA : a2nP;
    float4 av0 = *(const float4*)(a2 + fl * 8);
    float4 av1 = *(const float4*)(a2 + fl * 8 + 4);
    float avf[8] = {av0.x, av0.y, av0.z, av0.w, av1.x, av1.y, av1.z, av1.w};

    float o[8], s = 0.f;
    #pragma unroll
    for (int j = 0; j < 8; ++j) {
        float v = acc[j] * inv;
        o[j] = v > 0.f ? v : (__expf(v) - 1.f);
        s = fmaf(o[j], avf[j], s);
    }
    #pragma unroll
    for (int m = 1; m <= 8; m <<= 1) s += __shfl_xor(s, m, 64);

    union { half_t h[8]; int4 v; } pk;
    #pragma unroll
    for (int j = 0; j < 8; ++j) pk.h[j] = (half_t)o[j];
    *(int4*)((isA ? hAout : hPout) + (size_t)n * NHID + fl * 8) = pk.v;
    if (fl == 0) (isA ? h1Aout : h1Pout)[n] = s;
}

extern "C" void kernel_launch(void* const* d_in, const int* in_sizes, int n_in,
                              void* d_out, int out_size, void* d_ws, size_t ws_size,
                              hipStream_t stream)
{
    const float* x_A  = (const float*)d_in[0];
    const float* x_P  = (const float*)d_in[1];
    const int*   sAP  = (const int*)d_in[2];
    const int*   tAP  = (const int*)d_in[3];
    const int*   sPA  = (const int*)d_in[4];
    const int*   tPA  = (const int*)d_in[5];
    const float* W1_A = (const float*)d_in[6];
    const float* b1_A = (const float*)d_in[7];
    const float* W1_P = (const float*)d_in[8];
    const float* b1_P = (const float*)d_in[9];
    const float* attn1 = (const float*)d_in[10];
    const float* attn2 = (const float*)d_in[11];
    const float* W2   = (const float*)d_in[12];
    const float* b2   = (const float*)d_in[13];
    float* out = (float*)d_out;
    int nE = in_sizes[2];

    char* ws = (char*)d_ws;
    size_t off = 0;
    auto alloc = [&](size_t bytes) -> void* {
        void* p = ws + off;
        off += (bytes + 255) & ~(size_t)255;
        return p;
    };
    half_t* xAh  = (half_t*)alloc((size_t)NA * NHID * 2);
    half_t* xPh  = (half_t*)alloc((size_t)NP * NHID * 2);
    half_t* hAh[2] = {(half_t*)alloc((size_t)NA * NHID * 2),
                      (half_t*)alloc((size_t)NA * NHID * 2)};
    half_t* hPh[2] = {(half_t*)alloc((size_t)NP * NHID * 2),
                      (half_t*)alloc((size_t)NP * NHID * 2)};
    float* x1A = (float*)alloc((size_t)3 * NA * 4);
    float* w2A = (float*)alloc((size_t)3 * NA * 4);
    float* x1P = (float*)alloc((size_t)3 * NP * 4);
    float* w2P = (float*)alloc((size_t)3 * NP * 4);
    float* h1Ai = (float*)alloc(NA * 4);
    float* h1Pi = (float*)alloc(NP * 4);
    float* h1Ab[2] = {(float*)alloc(NA * 4), (float*)alloc(NA * 4)};
    float* h1Pb[2] = {(float*)alloc(NP * 4), (float*)alloc(NP * 4)};
    int* cntA  = (int*)alloc(NA * 4);
    int* cntP  = (int*)alloc(NP * 4);
    int* slotsA = (int*)alloc((size_t)NA * CAP_A * 4);
    int* slotsP = (int*)alloc((size_t)NP * CAP_P * 4);
    half_t* WtA = (half_t*)alloc((size_t)NHID * NIN * 2);
    half_t* WtP = (half_t*)alloc((size_t)NHID * NIN * 2);
    half_t* Wt2 = (half_t*)alloc((size_t)NOUT * NHID * 2);

    // weights -> f16 transposed + cnt zeroing (before fill)
    int prepN = 2 * NHID * NIN + NOUT * NHID + NA + NP;
    prep_all<<<(prepN + 255) / 256, 256, 0, stream>>>(W1_A, W1_P, W2, WtA, WtP, Wt2,
                                                      cntA, cntP);

    // padded CSR (edge structure reused by all hops)
    fill_kernel<<<(2 * nE + 255) / 256, 256, 0, stream>>>(sAP, tAP, sPA, tPA,
                                                          cntA, slotsA, cntP, slotsP, nE);

    // projections -> f16 h0
    proj_mfma<<<(NA + 63) / 64, 256, 0, stream>>>(x_A, WtA, b1_A, xAh, NA);
    proj_mfma<<<(NP + 63) / 64, 256, 0, stream>>>(x_P, WtP, b1_P, xPh, NP);

    // x-side scalars for all hops (merged)
    xdots_kernel<<<(NA + NP + 3) / 4, 256, 0, stream>>>(
        xAh, xPh, attn1, attn2, x1A, w2A, h1Ai, x1P, w2P, h1Pi);

    const half_t* hAg = xAh;
    const half_t* hPg = xPh;
    const float* h1Ac = h1Ai;
    const float* h1Pc = h1Pi;

    for (int i = 0; i < HOPS; ++i) {
        int last = (i == HOPS - 1);
        int nodes = last ? NA : (NA + NP);
        const float* a2nA_ = last ? attn2 : attn2 + (size_t)((i + 1) * 2 + 1) * NHID;
        const float* a2nP_ = last ? attn2 : attn2 + (size_t)((i + 1) * 2 + 0) * NHID;
        agg_fused<<<(nodes + 15) / 16, 256, 0, stream>>>(
            xAh, xPh, hAg, hPg,
            x1A + (size_t)i * NA, x1P + (size_t)i * NP,
            w2A + (size_t)i * NA, w2P + (size_t)i * NP,
            h1Ac, h1Pc,
            cntA, slotsA, cntP, slotsP,
            a2nA_, a2nP_,
            hAh[i & 1], hPh[i & 1], h1Ab[i & 1], h1Pb[i & 1],
            nodes);
        hAg = hAh[i & 1]; hPg = hPh[i & 1];
        h1Ac = h1Ab[i & 1]; h1Pc = h1Pb[i & 1];
    }

    out_mfma<<<(NA + 63) / 64, 256, 0, stream>>>(hAg, Wt2, b2, out, NA);
}

// Round 14
// 300.443 us; speedup vs baseline: 2.2422x; 1.1346x over previous
//
#include <hip/hip_runtime.h>
#include <hip/hip_bf16.h>
#include <hip/hip_fp16.h>

#define HOPS 3
#define NA 50000
#define NP 100000
#define NIN 256
#define NHID 128
#define NOUT 64
#define CAP_A 64
#define CAP_P 40

typedef _Float16 half_t;
typedef __attribute__((ext_vector_type(8))) _Float16 f16x8;
typedef __attribute__((ext_vector_type(4))) float f32x4;
typedef unsigned short ushort_t;

// async global -> LDS, 16 bytes per lane (linear dest: base + lane*16)
__device__ inline void gload16(const void* g, void* l) {
    __builtin_amdgcn_global_load_lds(
        (const __attribute__((address_space(1))) unsigned int*)g,
        (__attribute__((address_space(3))) unsigned int*)l, 16, 0, 0);
}

// ---------- weight transposes+converts (f16) + cnt zeroing (runs BEFORE fill) ----------
__global__ void prep_all(const float* __restrict__ W1_A, const float* __restrict__ W1_P,
                         const float* __restrict__ W2,
                         half_t* __restrict__ WtA, half_t* __restrict__ WtP,
                         half_t* __restrict__ Wt2,
                         int* __restrict__ cntA, int* __restrict__ cntP)
{
    int idx = blockIdx.x * 256 + threadIdx.x;
    const int S1 = NHID * NIN;
    const int SW = 2 * S1 + NOUT * NHID;
    if (idx < S1) {
        int n = idx / NIN, k = idx - n * NIN;
        WtA[idx] = (half_t)W1_A[(size_t)k * NHID + n];
    } else if (idx < 2 * S1) {
        int j = idx - S1;
        int n = j / NIN, k = j - n * NIN;
        WtP[j] = (half_t)W1_P[(size_t)k * NHID + n];
    } else if (idx < SW) {
        int j = idx - 2 * S1;
        int n = j / NHID, k = j - n * NHID;
        Wt2[j] = (half_t)W2[(size_t)k * NOUT + n];
    } else if (idx < SW + NA) {
        cntA[idx - SW] = 0;
    } else if (idx < SW + NA + NP) {
        cntP[idx - SW - NA] = 0;
    }
}

// ---------- projection (R2/R9 measured-best structure, f16) ----------
__global__ __launch_bounds__(256) void proj_mfma(const float* __restrict__ A,
                                                 const half_t* __restrict__ Wt,
                                                 const float* __restrict__ b,
                                                 half_t* __restrict__ Chf, int M)
{
    __shared__ half_t Alds[64][40];
    __shared__ half_t Wlds[128][40];
    int tid = threadIdx.x;
    int br = blockIdx.x * 64;
    int wv = tid >> 6;
    int l = tid & 63;
    int fl = l & 15;
    int kg = l >> 4;

    int sr = tid >> 2;
    int skp = (tid & 3) * 8;
    int sgr = br + sr; if (sgr >= M) sgr = M - 1;
    int sn = tid >> 1;
    int skq = (tid & 1) * 16;

    f32x4 acc[8];
    #pragma unroll
    for (int c = 0; c < 8; ++c) acc[c] = (f32x4){0.f, 0.f, 0.f, 0.f};

    for (int k0 = 0; k0 < NIN; k0 += 32) {
        const float4* ap = (const float4*)(A + (size_t)sgr * NIN + k0 + skp);
        float4 v0 = ap[0], v1 = ap[1];
        union { half_t s[8]; int4 v; } pk;
        pk.s[0] = (half_t)v0.x; pk.s[1] = (half_t)v0.y;
        pk.s[2] = (half_t)v0.z; pk.s[3] = (half_t)v0.w;
        pk.s[4] = (half_t)v1.x; pk.s[5] = (half_t)v1.y;
        pk.s[6] = (half_t)v1.z; pk.s[7] = (half_t)v1.w;
        *(int4*)&Alds[sr][skp] = pk.v;
        const int4* wp = (const int4*)(Wt + (size_t)sn * NIN + k0 + skq);
        int4 w0 = wp[0], w1 = wp[1];
        *(int4*)&Wlds[sn][skq] = w0;
        *(int4*)&Wlds[sn][skq + 8] = w1;
        __syncthreads();

        f16x8 afr = *(f16x8*)&Alds[wv * 16 + fl][kg * 8];
        #pragma unroll
        for (int c = 0; c < 8; ++c) {
            f16x8 bfr = *(f16x8*)&Wlds[c * 16 + fl][kg * 8];
            acc[c] = __builtin_amdgcn_mfma_f32_16x16x32_f16(afr, bfr, acc[c], 0, 0, 0);
        }
        __syncthreads();
    }

    int rj = kg * 4;
    #pragma unroll
    for (int c = 0; c < 8; ++c) {
        int col = c * 16 + fl;
        float bb = b[col];
        #pragma unroll
        for (int j = 0; j < 4; ++j) {
            int grow = br + wv * 16 + rj + j;
            if (grow < M) {
                float v = fmaxf(acc[c][j] + bb, 0.f);
                Chf[(size_t)grow * NHID + col] = (half_t)v;
            }
        }
    }
}

// ---------- output: C[M,64] = Ahf[M,128] @ W2 + b2, single-stage f16 MFMA ----------
__global__ __launch_bounds__(256) void out_mfma(const half_t* __restrict__ Ahf,
        const half_t* __restrict__ Wt, const float* __restrict__ b,
        float* __restrict__ C, int M)
{
    __shared__ half_t Sb[64 * 128];
    const int tid = threadIdx.x;
    const int wv = tid >> 6, l = tid & 63;
    const int fl = l & 15, kg = l >> 4;
    const int br = blockIdx.x * 64;
    const int srow = l >> 4, schk = l & 15;

    #pragma unroll
    for (int i = 0; i < 4; ++i) {
        int r = (wv * 4 + i) * 4 + srow;
        int gr = br + r; if (gr >= M) gr = M - 1;
        int ck = (schk ^ (r & 7)) * 8;
        gload16(Ahf + (size_t)gr * NHID + ck, &Sb[(wv * 4 + i) * 512]);
    }

    f32x4 acc[4];
    #pragma unroll
    for (int c = 0; c < 4; ++c) acc[c] = (f32x4){0.f, 0.f, 0.f, 0.f};

    f16x8 Bf[16];
    #pragma unroll
    for (int ks = 0; ks < 4; ++ks)
        #pragma unroll
        for (int cc = 0; cc < 4; ++cc)
            Bf[ks * 4 + cc] = *(const f16x8*)(Wt + (size_t)(cc * 16 + fl) * NHID
                                              + ks * 32 + kg * 8);
    __syncthreads();

    const int R = wv * 16 + fl;
    const int rx = R & 7;
    #pragma unroll
    for (int ks = 0; ks < 4; ++ks) {
        int chunk = (ks * 4 + kg) ^ rx;
        f16x8 af = *(const f16x8*)&Sb[R * 128 + chunk * 8];
        #pragma unroll
        for (int cc = 0; cc < 4; ++cc)
            acc[cc] = __builtin_amdgcn_mfma_f32_16x16x32_f16(af, Bf[ks * 4 + cc],
                                                             acc[cc], 0, 0, 0);
    }

    #pragma unroll
    for (int cc = 0; cc < 4; ++cc) {
        int col = cc * 16 + fl;
        float bb = b[col];
        #pragma unroll
        for (int j = 0; j < 4; ++j) {
            int grow = br + wv * 16 + kg * 4 + j;
            if (grow < M) C[(size_t)grow * NOUT + col] = acc[cc][j] + bb;
        }
    }
}

// ---------- merged padded-CSR fill ----------
__global__ void fill_kernel(const int* __restrict__ sA, const int* __restrict__ tA,
                            const int* __restrict__ sP, const int* __restrict__ tP,
                            int* __restrict__ cntA, int* __restrict__ slotsA,
                            int* __restrict__ cntP, int* __restrict__ slotsP, int nE)
{
    int e = blockIdx.x * 256 + threadIdx.x;
    if (e < nE) {
        int si = sA[e];
        int c = atomicAdd(&cntA[si], 1);
        if (c < CAP_A) slotsA[(size_t)si * CAP_A + c] = tA[e];
    } else if (e < 2 * nE) {
        int k = e - nE;
        int si = sP[k];
        int c = atomicAdd(&cntP[si], 1);
        if (c < CAP_P) slotsP[(size_t)si * CAP_P + c] = tP[k];
    }
}

// ---------- x-side scalars for ALL hops: 4 NODES PER WAVE, 16 lanes/node ----------
// Lane owns 8 features of its group's node. 7 dots (x.a1[i], x.a2[i], i=0..2;
// x.a2o) via 8 fma each + 4-step group reduce (masks 1,2,4,8 stay in-group).
__global__ __launch_bounds__(256) void xdots_kernel(
    const half_t* __restrict__ xAh, const half_t* __restrict__ xPh,
    const float* __restrict__ attn1, const float* __restrict__ attn2,
    float* __restrict__ x1A, float* __restrict__ w2A, float* __restrict__ h1Ai,
    float* __restrict__ x1P, float* __restrict__ w2P, float* __restrict__ h1Pi)
{
    int tid = threadIdx.x;
    int lane = tid & 63;
    int grp = lane >> 4, fl = lane & 15;
    int wid = (blockIdx.x * 256 + tid) >> 6;
    int ng = wid * 4 + grp;
    if (ng >= NA + NP) return;
    bool isA = ng < NA;
    int n = isA ? ng : ng - NA;
    int etype = isA ? 0 : 1;

    const half_t* x = (isA ? xAh : xPh) + (size_t)n * NHID + fl * 8;
    union { int4 v; half_t h[8]; } xc;
    xc.v = *(const int4*)x;
    float xf[8];
    #pragma unroll
    for (int j = 0; j < 8; ++j) xf[j] = (float)xc.h[j];

    float s[7];
    #pragma unroll
    for (int i = 0; i < 3; ++i) {
        const float* a1 = attn1 + (size_t)(i * 2 + etype) * NHID + fl * 8;
        const float* a2 = attn2 + (size_t)(i * 2 + etype) * NHID + fl * 8;
        float4 p0 = *(const float4*)a1, p1 = *(const float4*)(a1 + 4);
        float4 q0 = *(const float4*)a2, q1 = *(const float4*)(a2 + 4);
        float t1 = xf[0] * p0.x + xf[1] * p0.y + xf[2] * p0.z + xf[3] * p0.w
                 + xf[4] * p1.x + xf[5] * p1.y + xf[6] * p1.z + xf[7] * p1.w;
        float t2 = xf[0] * q0.x + xf[1] * q0.y + xf[2] * q0.z + xf[3] * q0.w
                 + xf[4] * q1.x + xf[5] * q1.y + xf[6] * q1.z + xf[7] * q1.w;
        s[i] = t1;
        s[3 + i] = t2;
    }
    {
        const float* a2o = attn2 + (size_t)(1 - etype) * NHID + fl * 8;
        float4 q0 = *(const float4*)a2o, q1 = *(const float4*)(a2o + 4);
        s[6] = xf[0] * q0.x + xf[1] * q0.y + xf[2] * q0.z + xf[3] * q0.w
             + xf[4] * q1.x + xf[5] * q1.y + xf[6] * q1.z + xf[7] * q1.w;
    }
    #pragma unroll
    for (int m = 1; m <= 8; m <<= 1)
        #pragma unroll
        for (int i = 0; i < 7; ++i) s[i] += __shfl_xor(s[i], m, 64);

    if (fl == 0) {
        int N = isA ? NA : NP;
        float* x1 = isA ? x1A : x1P;
        float* w2 = isA ? w2A : w2P;
        #pragma unroll
        for (int i = 0; i < 3; ++i) {
            x1[(size_t)i * N + n] = s[i];
            float v = s[i] + s[3 + i];
            v = v > 0.f ? v : 0.2f * v;
            w2[(size_t)i * N + n] = __expf(v);
        }
        (isA ? h1Ai : h1Pi)[n] = s[6];
    }
}

// ---------- fused A+P aggregation: 4 NODES PER WAVE, 16 lanes per node ----------
__global__ __launch_bounds__(256) void agg_fused(
    const half_t* __restrict__ xAh, const half_t* __restrict__ xPh,
    const half_t* __restrict__ hAg, const half_t* __restrict__ hPg,
    const float* __restrict__ x1Ah, const float* __restrict__ x1Ph,
    const float* __restrict__ w2Ah, const float* __restrict__ w2Ph,
    const float* __restrict__ h1Agc, const float* __restrict__ h1Pgc,
    const int* __restrict__ cntA, const int* __restrict__ slotsA,
    const int* __restrict__ cntP, const int* __restrict__ slotsP,
    const float* __restrict__ a2nA, const float* __restrict__ a2nP,
    half_t* __restrict__ hAout, half_t* __restrict__ hPout,
    float* __restrict__ h1Aout, float* __restrict__ h1Pout,
    int nodes)
{
    __shared__ float2 ew[4][4][16];   // [wave][group][slot] : (t as bits, w)
    int tid = threadIdx.x;
    int wv = tid >> 6;
    int lane = tid & 63;
    int grp = lane >> 4, fl = lane & 15;
    int wid = (blockIdx.x * 256 + tid) >> 6;
    int ng = wid * 4 + grp;
    if (ng >= nodes) return;
    bool isA = ng < NA;
    int n = isA ? ng : ng - NA;
    int deg; const int* sl; const half_t* hbf; const float* h1g; float x1v;
    if (isA) {
        deg = cntA[n]; if (deg > CAP_A) deg = CAP_A;
        sl = slotsA + (size_t)n * CAP_A; hbf = hPg; h1g = h1Pgc; x1v = x1Ah[n];
    } else {
        deg = cntP[n]; if (deg > CAP_P) deg = CAP_P;
        sl = slotsP + (size_t)n * CAP_P; hbf = hAg; h1g = h1Agc; x1v = x1Ph[n];
    }

    float acc[8] = {};
    float divacc = 0.f;

    for (int c0 = 0; c0 < deg; c0 += 16) {
        int idx = c0 + fl;
        int tl = 0; float wl = 0.f;
        if (idx < deg) {
            tl = sl[idx];
            float v = x1v + h1g[tl];
            v = v > 0.f ? v : 0.2f * v;
            wl = __expf(v);
        }
        divacc += wl;
        ew[wv][grp][fl] = make_float2(__int_as_float(tl), wl);

        int rounds = deg - c0; if (rounds > 16) rounds = 16;
        float2 tw = ew[wv][grp][0];
        int4 ra = *(const int4*)(hbf + (size_t)__float_as_int(tw.x) * NHID + fl * 8);
        for (int j = 0; j < rounds; ++j) {
            float w = tw.y;
            union { int4 v; half_t h[8]; } cur;
            cur.v = ra;
            if (j + 1 < rounds) {
                tw = ew[wv][grp][j + 1];
                ra = *(const int4*)(hbf + (size_t)__float_as_int(tw.x) * NHID + fl * 8);
            }
            acc[0] = fmaf(w, (float)cur.h[0], acc[0]);
            acc[1] = fmaf(w, (float)cur.h[1], acc[1]);
            acc[2] = fmaf(w, (float)cur.h[2], acc[2]);
            acc[3] = fmaf(w, (float)cur.h[3], acc[3]);
            acc[4] = fmaf(w, (float)cur.h[4], acc[4]);
            acc[5] = fmaf(w, (float)cur.h[5], acc[5]);
            acc[6] = fmaf(w, (float)cur.h[6], acc[6]);
            acc[7] = fmaf(w, (float)cur.h[7], acc[7]);
        }
    }

    // div reduce within the 16-lane group
    #pragma unroll
    for (int m = 1; m <= 8; m <<= 1) divacc += __shfl_xor(divacc, m, 64);

    // self term + epilogue: each lane finishes its 8 features
    float w2v = isA ? w2Ah[n] : w2Ph[n];
    const half_t* xb = (isA ? xAh : xPh) + (size_t)n * NHID + fl * 8;
    union { int4 v; half_t h[8]; } xc;
    xc.v = *(const int4*)xb;
    #pragma unroll
    for (int j = 0; j < 8; ++j) acc[j] = fmaf(w2v, (float)xc.h[j], acc[j]);
    float dv = divacc + w2v;
    float inv = 1.f / dv;

    const float* a2 = isA ? a2nA : a2nP;
    float4 av0 = *(const float4*)(a2 + fl * 8);
    float4 av1 = *(const float4*)(a2 + fl * 8 + 4);
    float avf[8] = {av0.x, av0.y, av0.z, av0.w, av1.x, av1.y, av1.z, av1.w};

    float o[8], s = 0.f;
    #pragma unroll
    for (int j = 0; j < 8; ++j) {
        float v = acc[j] * inv;
        o[j] = v > 0.f ? v : (__expf(v) - 1.f);
        s = fmaf(o[j], avf[j], s);
    }
    #pragma unroll
    for (int m = 1; m <= 8; m <<= 1) s += __shfl_xor(s, m, 64);

    union { half_t h[8]; int4 v; } pk;
    #pragma unroll
    for (int j = 0; j < 8; ++j) pk.h[j] = (half_t)o[j];
    *(int4*)((isA ? hAout : hPout) + (size_t)n * NHID + fl * 8) = pk.v;
    if (fl == 0) (isA ? h1Aout : h1Pout)[n] = s;
}

extern "C" void kernel_launch(void* const* d_in, const int* in_sizes, int n_in,
                              void* d_out, int out_size, void* d_ws, size_t ws_size,
                              hipStream_t stream)
{
    const float* x_A  = (const float*)d_in[0];
    const float* x_P  = (const float*)d_in[1];
    const int*   sAP  = (const int*)d_in[2];
    const int*   tAP  = (const int*)d_in[3];
    const int*   sPA  = (const int*)d_in[4];
    const int*   tPA  = (const int*)d_in[5];
    const float* W1_A = (const float*)d_in[6];
    const float* b1_A = (const float*)d_in[7];
    const float* W1_P = (const float*)d_in[8];
    const float* b1_P = (const float*)d_in[9];
    const float* attn1 = (const float*)d_in[10];
    const float* attn2 = (const float*)d_in[11];
    const float* W2   = (const float*)d_in[12];
    const float* b2   = (const float*)d_in[13];
    float* out = (float*)d_out;
    int nE = in_sizes[2];

    char* ws = (char*)d_ws;
    size_t off = 0;
    auto alloc = [&](size_t bytes) -> void* {
        void* p = ws + off;
        off += (bytes + 255) & ~(size_t)255;
        return p;
    };
    half_t* xAh  = (half_t*)alloc((size_t)NA * NHID * 2);
    half_t* xPh  = (half_t*)alloc((size_t)NP * NHID * 2);
    half_t* hAh[2] = {(half_t*)alloc((size_t)NA * NHID * 2),
                      (half_t*)alloc((size_t)NA * NHID * 2)};
    half_t* hPh[2] = {(half_t*)alloc((size_t)NP * NHID * 2),
                      (half_t*)alloc((size_t)NP * NHID * 2)};
    float* x1A = (float*)alloc((size_t)3 * NA * 4);
    float* w2A = (float*)alloc((size_t)3 * NA * 4);
    float* x1P = (float*)alloc((size_t)3 * NP * 4);
    float* w2P = (float*)alloc((size_t)3 * NP * 4);
    float* h1Ai = (float*)alloc(NA * 4);
    float* h1Pi = (float*)alloc(NP * 4);
    float* h1Ab[2] = {(float*)alloc(NA * 4), (float*)alloc(NA * 4)};
    float* h1Pb[2] = {(float*)alloc(NP * 4), (float*)alloc(NP * 4)};
    int* cntA  = (int*)alloc(NA * 4);
    int* cntP  = (int*)alloc(NP * 4);
    int* slotsA = (int*)alloc((size_t)NA * CAP_A * 4);
    int* slotsP = (int*)alloc((size_t)NP * CAP_P * 4);
    half_t* WtA = (half_t*)alloc((size_t)NHID * NIN * 2);
    half_t* WtP = (half_t*)alloc((size_t)NHID * NIN * 2);
    half_t* Wt2 = (half_t*)alloc((size_t)NOUT * NHID * 2);

    // weights -> f16 transposed + cnt zeroing (before fill)
    int prepN = 2 * NHID * NIN + NOUT * NHID + NA + NP;
    prep_all<<<(prepN + 255) / 256, 256, 0, stream>>>(W1_A, W1_P, W2, WtA, WtP, Wt2,
                                                      cntA, cntP);

    // padded CSR (edge structure reused by all hops)
    fill_kernel<<<(2 * nE + 255) / 256, 256, 0, stream>>>(sAP, tAP, sPA, tPA,
                                                          cntA, slotsA, cntP, slotsP, nE);

    // projections -> f16 h0
    proj_mfma<<<(NA + 63) / 64, 256, 0, stream>>>(x_A, WtA, b1_A, xAh, NA);
    proj_mfma<<<(NP + 63) / 64, 256, 0, stream>>>(x_P, WtP, b1_P, xPh, NP);

    // x-side scalars for all hops (4 nodes/wave)
    xdots_kernel<<<(NA + NP + 15) / 16, 256, 0, stream>>>(
        xAh, xPh, attn1, attn2, x1A, w2A, h1Ai, x1P, w2P, h1Pi);

    const half_t* hAg = xAh;
    const half_t* hPg = xPh;
    const float* h1Ac = h1Ai;
    const float* h1Pc = h1Pi;

    for (int i = 0; i < HOPS; ++i) {
        int last = (i == HOPS - 1);
        int nodes = last ? NA : (NA + NP);
        const float* a2nA_ = last ? attn2 : attn2 + (size_t)((i + 1) * 2 + 1) * NHID;
        const float* a2nP_ = last ? attn2 : attn2 + (size_t)((i + 1) * 2 + 0) * NHID;
        agg_fused<<<(nodes + 15) / 16, 256, 0, stream>>>(
            xAh, xPh, hAg, hPg,
            x1A + (size_t)i * NA, x1P + (size_t)i * NP,
            w2A + (size_t)i * NA, w2P + (size_t)i * NP,
            h1Ac, h1Pc,
            cntA, slotsA, cntP, slotsP,
            a2nA_, a2nP_,
            hAh[i & 1], hPh[i & 1], h1Ab[i & 1], h1Pb[i & 1],
            nodes);
        hAg = hAh[i & 1]; hPg = hPh[i & 1];
        h1Ac = h1Ab[i & 1]; h1Pc = h1Pb[i & 1];
    }

    out_mfma<<<(NA + 63) / 64, 256, 0, stream>>>(hAg, Wt2, b2, out, NA);
}

// Round 15
// 267.936 us; speedup vs baseline: 2.5142x; 1.1213x over previous
//
#include <hip/hip_runtime.h>
#include <hip/hip_bf16.h>
#include <hip/hip_fp16.h>

#define HOPS 3
#define NA 50000
#define NP 100000
#define NIN 256
#define NHID 128
#define NOUT 64
#define CAP_A 64
#define CAP_P 40

typedef _Float16 half_t;
typedef __attribute__((ext_vector_type(8))) _Float16 f16x8;
typedef __attribute__((ext_vector_type(4))) float f32x4;
typedef unsigned short ushort_t;

// async global -> LDS, 16 bytes per lane (linear dest: base + lane*16)
__device__ inline void gload16(const void* g, void* l) {
    __builtin_amdgcn_global_load_lds(
        (const __attribute__((address_space(1))) unsigned int*)g,
        (__attribute__((address_space(3))) unsigned int*)l, 16, 0, 0);
}

// ---------- weight transposes+converts (f16) + cnt zeroing (runs BEFORE fused) ----------
__global__ void prep_all(const float* __restrict__ W1_A, const float* __restrict__ W1_P,
                         const float* __restrict__ W2,
                         half_t* __restrict__ WtA, half_t* __restrict__ WtP,
                         half_t* __restrict__ Wt2,
                         int* __restrict__ cntA, int* __restrict__ cntP)
{
    int idx = blockIdx.x * 256 + threadIdx.x;
    const int S1 = NHID * NIN;
    const int SW = 2 * S1 + NOUT * NHID;
    if (idx < S1) {
        int n = idx / NIN, k = idx - n * NIN;
        WtA[idx] = (half_t)W1_A[(size_t)k * NHID + n];
    } else if (idx < 2 * S1) {
        int j = idx - S1;
        int n = j / NIN, k = j - n * NIN;
        WtP[j] = (half_t)W1_P[(size_t)k * NHID + n];
    } else if (idx < SW) {
        int j = idx - 2 * S1;
        int n = j / NHID, k = j - n * NHID;
        Wt2[j] = (half_t)W2[(size_t)k * NOUT + n];
    } else if (idx < SW + NA) {
        cntA[idx - SW] = 0;
    } else if (idx < SW + NA + NP) {
        cntP[idx - SW - NA] = 0;
    }
}

// ---------- FUSED: proj(A) blocks [0,gA) | proj(P) blocks [gA,gAB) | fill rest ----------
// proj: R2/R9 measured-best structure (f16). fill: padded-CSR scatter (latency-
// bound, no busy pipe) co-resident with MFMA/LDS-bound proj -> overlap.
__global__ __launch_bounds__(256) void fused_proj_fill(
        const float* __restrict__ xA, const float* __restrict__ xP,
        const half_t* __restrict__ WtA_, const half_t* __restrict__ WtP_,
        const float* __restrict__ bA, const float* __restrict__ bP,
        half_t* __restrict__ CA, half_t* __restrict__ CP,
        const int* __restrict__ sA, const int* __restrict__ tA,
        const int* __restrict__ sP, const int* __restrict__ tP,
        int* __restrict__ cntA, int* __restrict__ slotsA,
        int* __restrict__ cntP, int* __restrict__ slotsP,
        int nE, int gA, int gAB)
{
    __shared__ half_t Alds[64][40];
    __shared__ half_t Wlds[128][40];
    const int bid = blockIdx.x;
    const int tid = threadIdx.x;

    if (bid >= gAB) {
        // ---------------- fill part ----------------
        int e = (bid - gAB) * 256 + tid;
        if (e < nE) {
            int si = sA[e];
            int c = atomicAdd(&cntA[si], 1);
            if (c < CAP_A) slotsA[(size_t)si * CAP_A + c] = tA[e];
        } else if (e < 2 * nE) {
            int k = e - nE;
            int si = sP[k];
            int c = atomicAdd(&cntP[si], 1);
            if (c < CAP_P) slotsP[(size_t)si * CAP_P + c] = tP[k];
        }
        return;
    }

    // ---------------- proj part ----------------
    const bool isA = bid < gA;
    const float* A = isA ? xA : xP;
    const half_t* Wt = isA ? WtA_ : WtP_;
    const float* bias = isA ? bA : bP;
    half_t* Chf = isA ? CA : CP;
    const int M = isA ? NA : NP;
    const int br = (isA ? bid : bid - gA) * 64;

    int wv = tid >> 6;
    int l = tid & 63;
    int fl = l & 15;
    int kg = l >> 4;

    int sr = tid >> 2;
    int skp = (tid & 3) * 8;
    int sgr = br + sr; if (sgr >= M) sgr = M - 1;
    int sn = tid >> 1;
    int skq = (tid & 1) * 16;

    f32x4 acc[8];
    #pragma unroll
    for (int c = 0; c < 8; ++c) acc[c] = (f32x4){0.f, 0.f, 0.f, 0.f};

    for (int k0 = 0; k0 < NIN; k0 += 32) {
        const float4* ap = (const float4*)(A + (size_t)sgr * NIN + k0 + skp);
        float4 v0 = ap[0], v1 = ap[1];
        union { half_t s[8]; int4 v; } pk;
        pk.s[0] = (half_t)v0.x; pk.s[1] = (half_t)v0.y;
        pk.s[2] = (half_t)v0.z; pk.s[3] = (half_t)v0.w;
        pk.s[4] = (half_t)v1.x; pk.s[5] = (half_t)v1.y;
        pk.s[6] = (half_t)v1.z; pk.s[7] = (half_t)v1.w;
        *(int4*)&Alds[sr][skp] = pk.v;
        const int4* wp = (const int4*)(Wt + (size_t)sn * NIN + k0 + skq);
        int4 w0 = wp[0], w1 = wp[1];
        *(int4*)&Wlds[sn][skq] = w0;
        *(int4*)&Wlds[sn][skq + 8] = w1;
        __syncthreads();

        f16x8 afr = *(f16x8*)&Alds[wv * 16 + fl][kg * 8];
        #pragma unroll
        for (int c = 0; c < 8; ++c) {
            f16x8 bfr = *(f16x8*)&Wlds[c * 16 + fl][kg * 8];
            acc[c] = __builtin_amdgcn_mfma_f32_16x16x32_f16(afr, bfr, acc[c], 0, 0, 0);
        }
        __syncthreads();
    }

    int rj = kg * 4;
    #pragma unroll
    for (int c = 0; c < 8; ++c) {
        int col = c * 16 + fl;
        float bb = bias[col];
        #pragma unroll
        for (int j = 0; j < 4; ++j) {
            int grow = br + wv * 16 + rj + j;
            if (grow < M) {
                float v = fmaxf(acc[c][j] + bb, 0.f);
                Chf[(size_t)grow * NHID + col] = (half_t)v;
            }
        }
    }
}

// ---------- output: C[M,64] = Ahf[M,128] @ W2 + b2, single-stage f16 MFMA ----------
__global__ __launch_bounds__(256) void out_mfma(const half_t* __restrict__ Ahf,
        const half_t* __restrict__ Wt, const float* __restrict__ b,
        float* __restrict__ C, int M)
{
    __shared__ half_t Sb[64 * 128];
    const int tid = threadIdx.x;
    const int wv = tid >> 6, l = tid & 63;
    const int fl = l & 15, kg = l >> 4;
    const int br = blockIdx.x * 64;
    const int srow = l >> 4, schk = l & 15;

    #pragma unroll
    for (int i = 0; i < 4; ++i) {
        int r = (wv * 4 + i) * 4 + srow;
        int gr = br + r; if (gr >= M) gr = M - 1;
        int ck = (schk ^ (r & 7)) * 8;
        gload16(Ahf + (size_t)gr * NHID + ck, &Sb[(wv * 4 + i) * 512]);
    }

    f32x4 acc[4];
    #pragma unroll
    for (int c = 0; c < 4; ++c) acc[c] = (f32x4){0.f, 0.f, 0.f, 0.f};

    f16x8 Bf[16];
    #pragma unroll
    for (int ks = 0; ks < 4; ++ks)
        #pragma unroll
        for (int cc = 0; cc < 4; ++cc)
            Bf[ks * 4 + cc] = *(const f16x8*)(Wt + (size_t)(cc * 16 + fl) * NHID
                                              + ks * 32 + kg * 8);
    __syncthreads();

    const int R = wv * 16 + fl;
    const int rx = R & 7;
    #pragma unroll
    for (int ks = 0; ks < 4; ++ks) {
        int chunk = (ks * 4 + kg) ^ rx;
        f16x8 af = *(const f16x8*)&Sb[R * 128 + chunk * 8];
        #pragma unroll
        for (int cc = 0; cc < 4; ++cc)
            acc[cc] = __builtin_amdgcn_mfma_f32_16x16x32_f16(af, Bf[ks * 4 + cc],
                                                             acc[cc], 0, 0, 0);
    }

    #pragma unroll
    for (int cc = 0; cc < 4; ++cc) {
        int col = cc * 16 + fl;
        float bb = b[col];
        #pragma unroll
        for (int j = 0; j < 4; ++j) {
            int grow = br + wv * 16 + kg * 4 + j;
            if (grow < M) C[(size_t)grow * NOUT + col] = acc[cc][j] + bb;
        }
    }
}

// ---------- x-side scalars for ALL hops: 4 NODES PER WAVE, 16 lanes/node ----------
__global__ __launch_bounds__(256) void xdots_kernel(
    const half_t* __restrict__ xAh, const half_t* __restrict__ xPh,
    const float* __restrict__ attn1, const float* __restrict__ attn2,
    float* __restrict__ x1A, float* __restrict__ w2A, float* __restrict__ h1Ai,
    float* __restrict__ x1P, float* __restrict__ w2P, float* __restrict__ h1Pi)
{
    int tid = threadIdx.x;
    int lane = tid & 63;
    int grp = lane >> 4, fl = lane & 15;
    int wid = (blockIdx.x * 256 + tid) >> 6;
    int ng = wid * 4 + grp;
    if (ng >= NA + NP) return;
    bool isA = ng < NA;
    int n = isA ? ng : ng - NA;
    int etype = isA ? 0 : 1;

    const half_t* x = (isA ? xAh : xPh) + (size_t)n * NHID + fl * 8;
    union { int4 v; half_t h[8]; } xc;
    xc.v = *(const int4*)x;
    float xf[8];
    #pragma unroll
    for (int j = 0; j < 8; ++j) xf[j] = (float)xc.h[j];

    float s[7];
    #pragma unroll
    for (int i = 0; i < 3; ++i) {
        const float* a1 = attn1 + (size_t)(i * 2 + etype) * NHID + fl * 8;
        const float* a2 = attn2 + (size_t)(i * 2 + etype) * NHID + fl * 8;
        float4 p0 = *(const float4*)a1, p1 = *(const float4*)(a1 + 4);
        float4 q0 = *(const float4*)a2, q1 = *(const float4*)(a2 + 4);
        float t1 = xf[0] * p0.x + xf[1] * p0.y + xf[2] * p0.z + xf[3] * p0.w
                 + xf[4] * p1.x + xf[5] * p1.y + xf[6] * p1.z + xf[7] * p1.w;
        float t2 = xf[0] * q0.x + xf[1] * q0.y + xf[2] * q0.z + xf[3] * q0.w
                 + xf[4] * q1.x + xf[5] * q1.y + xf[6] * q1.z + xf[7] * q1.w;
        s[i] = t1;
        s[3 + i] = t2;
    }
    {
        const float* a2o = attn2 + (size_t)(1 - etype) * NHID + fl * 8;
        float4 q0 = *(const float4*)a2o, q1 = *(const float4*)(a2o + 4);
        s[6] = xf[0] * q0.x + xf[1] * q0.y + xf[2] * q0.z + xf[3] * q0.w
             + xf[4] * q1.x + xf[5] * q1.y + xf[6] * q1.z + xf[7] * q1.w;
    }
    #pragma unroll
    for (int m = 1; m <= 8; m <<= 1)
        #pragma unroll
        for (int i = 0; i < 7; ++i) s[i] += __shfl_xor(s[i], m, 64);

    if (fl == 0) {
        int N = isA ? NA : NP;
        float* x1 = isA ? x1A : x1P;
        float* w2 = isA ? w2A : w2P;
        #pragma unroll
        for (int i = 0; i < 3; ++i) {
            x1[(size_t)i * N + n] = s[i];
            float v = s[i] + s[3 + i];
            v = v > 0.f ? v : 0.2f * v;
            w2[(size_t)i * N + n] = __expf(v);
        }
        (isA ? h1Ai : h1Pi)[n] = s[6];
    }
}

// ---------- fused A+P aggregation: 4 NODES PER WAVE, 16 lanes per node ----------
__global__ __launch_bounds__(256) void agg_fused(
    const half_t* __restrict__ xAh, const half_t* __restrict__ xPh,
    const half_t* __restrict__ hAg, const half_t* __restrict__ hPg,
    const float* __restrict__ x1Ah, const float* __restrict__ x1Ph,
    const float* __restrict__ w2Ah, const float* __restrict__ w2Ph,
    const float* __restrict__ h1Agc, const float* __restrict__ h1Pgc,
    const int* __restrict__ cntA, const int* __restrict__ slotsA,
    const int* __restrict__ cntP, const int* __restrict__ slotsP,
    const float* __restrict__ a2nA, const float* __restrict__ a2nP,
    half_t* __restrict__ hAout, half_t* __restrict__ hPout,
    float* __restrict__ h1Aout, float* __restrict__ h1Pout,
    int nodes)
{
    __shared__ float2 ew[4][4][16];   // [wave][group][slot] : (t as bits, w)
    int tid = threadIdx.x;
    int wv = tid >> 6;
    int lane = tid & 63;
    int grp = lane >> 4, fl = lane & 15;
    int wid = (blockIdx.x * 256 + tid) >> 6;
    int ng = wid * 4 + grp;
    if (ng >= nodes) return;
    bool isA = ng < NA;
    int n = isA ? ng : ng - NA;
    int deg; const int* sl; const half_t* hbf; const float* h1g; float x1v;
    if (isA) {
        deg = cntA[n]; if (deg > CAP_A) deg = CAP_A;
        sl = slotsA + (size_t)n * CAP_A; hbf = hPg; h1g = h1Pgc; x1v = x1Ah[n];
    } else {
        deg = cntP[n]; if (deg > CAP_P) deg = CAP_P;
        sl = slotsP + (size_t)n * CAP_P; hbf = hAg; h1g = h1Agc; x1v = x1Ph[n];
    }

    float acc[8] = {};
    float divacc = 0.f;

    for (int c0 = 0; c0 < deg; c0 += 16) {
        int idx = c0 + fl;
        int tl = 0; float wl = 0.f;
        if (idx < deg) {
            tl = sl[idx];
            float v = x1v + h1g[tl];
            v = v > 0.f ? v : 0.2f * v;
            wl = __expf(v);
        }
        divacc += wl;
        ew[wv][grp][fl] = make_float2(__int_as_float(tl), wl);

        int rounds = deg - c0; if (rounds > 16) rounds = 16;
        float2 tw = ew[wv][grp][0];
        int4 ra = *(const int4*)(hbf + (size_t)__float_as_int(tw.x) * NHID + fl * 8);
        for (int j = 0; j < rounds; ++j) {
            float w = tw.y;
            union { int4 v; half_t h[8]; } cur;
            cur.v = ra;
            if (j + 1 < rounds) {
                tw = ew[wv][grp][j + 1];
                ra = *(const int4*)(hbf + (size_t)__float_as_int(tw.x) * NHID + fl * 8);
            }
            acc[0] = fmaf(w, (float)cur.h[0], acc[0]);
            acc[1] = fmaf(w, (float)cur.h[1], acc[1]);
            acc[2] = fmaf(w, (float)cur.h[2], acc[2]);
            acc[3] = fmaf(w, (float)cur.h[3], acc[3]);
            acc[4] = fmaf(w, (float)cur.h[4], acc[4]);
            acc[5] = fmaf(w, (float)cur.h[5], acc[5]);
            acc[6] = fmaf(w, (float)cur.h[6], acc[6]);
            acc[7] = fmaf(w, (float)cur.h[7], acc[7]);
        }
    }

    // div reduce within the 16-lane group
    #pragma unroll
    for (int m = 1; m <= 8; m <<= 1) divacc += __shfl_xor(divacc, m, 64);

    // self term + epilogue: each lane finishes its 8 features
    float w2v = isA ? w2Ah[n] : w2Ph[n];
    const half_t* xb = (isA ? xAh : xPh) + (size_t)n * NHID + fl * 8;
    union { int4 v; half_t h[8]; } xc;
    xc.v = *(const int4*)xb;
    #pragma unroll
    for (int j = 0; j < 8; ++j) acc[j] = fmaf(w2v, (float)xc.h[j], acc[j]);
    float dv = divacc + w2v;
    float inv = 1.f / dv;

    const float* a2 = isA ? a2nA : a2nP;
    float4 av0 = *(const float4*)(a2 + fl * 8);
    float4 av1 = *(const float4*)(a2 + fl * 8 + 4);
    float avf[8] = {av0.x, av0.y, av0.z, av0.w, av1.x, av1.y, av1.z, av1.w};

    float o[8], s = 0.f;
    #pragma unroll
    for (int j = 0; j < 8; ++j) {
        float v = acc[j] * inv;
        o[j] = v > 0.f ? v : (__expf(v) - 1.f);
        s = fmaf(o[j], avf[j], s);
    }
    #pragma unroll
    for (int m = 1; m <= 8; m <<= 1) s += __shfl_xor(s, m, 64);

    union { half_t h[8]; int4 v; } pk;
    #pragma unroll
    for (int j = 0; j < 8; ++j) pk.h[j] = (half_t)o[j];
    *(int4*)((isA ? hAout : hPout) + (size_t)n * NHID + fl * 8) = pk.v;
    if (fl == 0) (isA ? h1Aout : h1Pout)[n] = s;
}

extern "C" void kernel_launch(void* const* d_in, const int* in_sizes, int n_in,
                              void* d_out, int out_size, void* d_ws, size_t ws_size,
                              hipStream_t stream)
{
    const float* x_A  = (const float*)d_in[0];
    const float* x_P  = (const float*)d_in[1];
    const int*   sAP  = (const int*)d_in[2];
    const int*   tAP  = (const int*)d_in[3];
    const int*   sPA  = (const int*)d_in[4];
    const int*   tPA  = (const int*)d_in[5];
    const float* W1_A = (const float*)d_in[6];
    const float* b1_A = (const float*)d_in[7];
    const float* W1_P = (const float*)d_in[8];
    const float* b1_P = (const float*)d_in[9];
    const float* attn1 = (const float*)d_in[10];
    const float* attn2 = (const float*)d_in[11];
    const float* W2   = (const float*)d_in[12];
    const float* b2   = (const float*)d_in[13];
    float* out = (float*)d_out;
    int nE = in_sizes[2];

    char* ws = (char*)d_ws;
    size_t off = 0;
    auto alloc = [&](size_t bytes) -> void* {
        void* p = ws + off;
        off += (bytes + 255) & ~(size_t)255;
        return p;
    };
    half_t* xAh  = (half_t*)alloc((size_t)NA * NHID * 2);
    half_t* xPh  = (half_t*)alloc((size_t)NP * NHID * 2);
    half_t* hAh[2] = {(half_t*)alloc((size_t)NA * NHID * 2),
                      (half_t*)alloc((size_t)NA * NHID * 2)};
    half_t* hPh[2] = {(half_t*)alloc((size_t)NP * NHID * 2),
                      (half_t*)alloc((size_t)NP * NHID * 2)};
    float* x1A = (float*)alloc((size_t)3 * NA * 4);
    float* w2A = (float*)alloc((size_t)3 * NA * 4);
    float* x1P = (float*)alloc((size_t)3 * NP * 4);
    float* w2P = (float*)alloc((size_t)3 * NP * 4);
    float* h1Ai = (float*)alloc(NA * 4);
    float* h1Pi = (float*)alloc(NP * 4);
    float* h1Ab[2] = {(float*)alloc(NA * 4), (float*)alloc(NA * 4)};
    float* h1Pb[2] = {(float*)alloc(NP * 4), (float*)alloc(NP * 4)};
    int* cntA  = (int*)alloc(NA * 4);
    int* cntP  = (int*)alloc(NP * 4);
    int* slotsA = (int*)alloc((size_t)NA * CAP_A * 4);
    int* slotsP = (int*)alloc((size_t)NP * CAP_P * 4);
    half_t* WtA = (half_t*)alloc((size_t)NHID * NIN * 2);
    half_t* WtP = (half_t*)alloc((size_t)NHID * NIN * 2);
    half_t* Wt2 = (half_t*)alloc((size_t)NOUT * NHID * 2);

    // weights -> f16 transposed + cnt zeroing (before fused kernel)
    int prepN = 2 * NHID * NIN + NOUT * NHID + NA + NP;
    prep_all<<<(prepN + 255) / 256, 256, 0, stream>>>(W1_A, W1_P, W2, WtA, WtP, Wt2,
                                                      cntA, cntP);

    // FUSED: proj(A) + proj(P) + padded-CSR fill in one dispatch (independent work)
    int gA = (NA + 63) / 64, gP = (NP + 63) / 64;
    int gAB = gA + gP;
    int fillBlocks = (2 * nE + 255) / 256;
    fused_proj_fill<<<gAB + fillBlocks, 256, 0, stream>>>(
        x_A, x_P, WtA, WtP, b1_A, b1_P, xAh, xPh,
        sAP, tAP, sPA, tPA, cntA, slotsA, cntP, slotsP,
        nE, gA, gAB);

    // x-side scalars for all hops (4 nodes/wave)
    xdots_kernel<<<(NA + NP + 15) / 16, 256, 0, stream>>>(
        xAh, xPh, attn1, attn2, x1A, w2A, h1Ai, x1P, w2P, h1Pi);

    const half_t* hAg = xAh;
    const half_t* hPg = xPh;
    const float* h1Ac = h1Ai;
    const float* h1Pc = h1Pi;

    for (int i = 0; i < HOPS; ++i) {
        int last = (i == HOPS - 1);
        int nodes = last ? NA : (NA + NP);
        const float* a2nA_ = last ? attn2 : attn2 + (size_t)((i + 1) * 2 + 1) * NHID;
        const float* a2nP_ = last ? attn2 : attn2 + (size_t)((i + 1) * 2 + 0) * NHID;
        agg_fused<<<(nodes + 15) / 16, 256, 0, stream>>>(
            xAh, xPh, hAg, hPg,
            x1A + (size_t)i * NA, x1P + (size_t)i * NP,
            w2A + (size_t)i * NA, w2P + (size_t)i * NP,
            h1Ac, h1Pc,
            cntA, slotsA, cntP, slotsP,
            a2nA_, a2nP_,
            hAh[i & 1], hPh[i & 1], h1Ab[i & 1], h1Pb[i & 1],
            nodes);
        hAg = hAh[i & 1]; hPg = hPh[i & 1];
        h1Ac = h1Ab[i & 1]; h1Pc = h1Pb[i & 1];
    }

    out_mfma<<<(NA + 63) / 64, 256, 0, stream>>>(hAg, Wt2, b2, out, NA);
}